// Round 1
// baseline (3626.870 us; speedup 1.0000x reference)
//
#include <hip/hip_runtime.h>
#include <hip/hip_bf16.h>

// Problem constants (match reference)
constexpr int Dm = 1024;   // model dim
constexpr int NH = 16;     // heads
constexpr int DH = 64;     // head dim
constexpr int Ff = 2048;   // FFN dim
constexpr int NE = 8;      // experts
constexpr int Bn = 4;      // batch
constexpr int Tn = 512;    // seq len
constexpr int Nt = 2048;   // total tokens = Bn*Tn

// ---------------------------------------------------------------------------
// Generic tiled fp32 GEMM: C[M x Nc] = A[M x Kd] @ W[Kd x Nc] + bias[Nc]
// 64x64 tile, K-step 16, 256 threads, 4x4 micro-tile per thread.
// Nc, Kd must be multiples of 64/16 (true for all our shapes). M guarded.
// ---------------------------------------------------------------------------
__global__ __launch_bounds__(256) void gemm_bias_kernel(
    const float* __restrict__ A, const float* __restrict__ W,
    const float* __restrict__ bias, float* __restrict__ C,
    int M, int Kd, int Nc)
{
    __shared__ float As[64][17];   // [m][k], +1 pad
    __shared__ float Ws[16][65];   // [k][n], +1 pad
    const int tidx = threadIdx.x;
    const int tx = tidx & 15, ty = tidx >> 4;
    const int m0 = blockIdx.y * 64, n0 = blockIdx.x * 64;
    float acc[4][4] = {};

    for (int k0 = 0; k0 < Kd; k0 += 16) {
        #pragma unroll
        for (int i = tidx; i < 64 * 16; i += 256) {
            int r = i >> 4, c = i & 15;
            int gr = m0 + r;
            As[r][c] = (gr < M) ? A[(size_t)gr * Kd + k0 + c] : 0.f;
        }
        #pragma unroll
        for (int i = tidx; i < 16 * 64; i += 256) {
            int r = i >> 6, c = i & 63;
            Ws[r][c] = W[(size_t)(k0 + r) * Nc + n0 + c];
        }
        __syncthreads();
        #pragma unroll
        for (int kk = 0; kk < 16; ++kk) {
            float a[4], b[4];
            #pragma unroll
            for (int i = 0; i < 4; ++i) a[i] = As[ty * 4 + i][kk];
            #pragma unroll
            for (int j = 0; j < 4; ++j) b[j] = Ws[kk][tx * 4 + j];
            #pragma unroll
            for (int i = 0; i < 4; ++i)
                #pragma unroll
                for (int j = 0; j < 4; ++j)
                    acc[i][j] += a[i] * b[j];
        }
        __syncthreads();
    }
    #pragma unroll
    for (int i = 0; i < 4; ++i) {
        int r = m0 + ty * 4 + i;
        if (r >= M) continue;
        #pragma unroll
        for (int j = 0; j < 4; ++j) {
            int c = n0 + tx * 4 + j;
            C[(size_t)r * Nc + c] = acc[i][j] + bias[c];
        }
    }
}

// ---------------------------------------------------------------------------
// Attention core: one block per (b, h, 16-query tile).
// scores = Q K^T / 8 -> softmax -> @V. Q/K/V in [b*T+t, h*64+d] layout.
// ---------------------------------------------------------------------------
__global__ __launch_bounds__(256) void attention_kernel(
    const float* __restrict__ Q, const float* __restrict__ Km,
    const float* __restrict__ V, float* __restrict__ O)
{
    const int qt = blockIdx.x, hh = blockIdx.y, b = blockIdx.z;
    __shared__ float Qs[16][65];
    __shared__ float KVs[64][65];
    __shared__ float Sc[16][513];
    const int tidx = threadIdx.x;
    const int baseQ = b * Tn + qt * 16;

    for (int i = tidx; i < 16 * 64; i += 256) {
        int r = i >> 6, c = i & 63;
        Qs[r][c] = Q[(size_t)(baseQ + r) * Dm + hh * 64 + c];
    }
    __syncthreads();

    const int q  = tidx >> 4;   // query row 0..15
    const int lx = tidx & 15;   // lane-in-group

    // ---- scores ----
    for (int kt0 = 0; kt0 < Tn; kt0 += 64) {
        for (int i = tidx; i < 64 * 64; i += 256) {
            int r = i >> 6, c = i & 63;
            KVs[r][c] = Km[(size_t)(b * Tn + kt0 + r) * Dm + hh * 64 + c];
        }
        __syncthreads();
        float s[4] = {0.f, 0.f, 0.f, 0.f};
        const int ktb = lx * 4;
        for (int d = 0; d < 64; ++d) {
            float qv = Qs[q][d];
            #pragma unroll
            for (int j = 0; j < 4; ++j) s[j] += qv * KVs[ktb + j][d];
        }
        #pragma unroll
        for (int j = 0; j < 4; ++j) Sc[q][kt0 + ktb + j] = s[j] * 0.125f;
        __syncthreads();
    }

    // ---- softmax over row q (16 lanes per row) ----
    float mx = -1e30f;
    for (int kt = lx; kt < Tn; kt += 16) mx = fmaxf(mx, Sc[q][kt]);
    #pragma unroll
    for (int off = 8; off; off >>= 1) mx = fmaxf(mx, __shfl_xor(mx, off));
    float sum = 0.f;
    for (int kt = lx; kt < Tn; kt += 16) {
        float p = __expf(Sc[q][kt] - mx);
        Sc[q][kt] = p;
        sum += p;
    }
    #pragma unroll
    for (int off = 8; off; off >>= 1) sum += __shfl_xor(sum, off);
    const float inv = 1.f / sum;
    __syncthreads();

    // ---- P @ V ----
    float o[4] = {0.f, 0.f, 0.f, 0.f};
    const int dB = lx * 4;
    for (int kt0 = 0; kt0 < Tn; kt0 += 64) {
        for (int i = tidx; i < 64 * 64; i += 256) {
            int r = i >> 6, c = i & 63;
            KVs[r][c] = V[(size_t)(b * Tn + kt0 + r) * Dm + hh * 64 + c];
        }
        __syncthreads();
        for (int k = 0; k < 64; ++k) {
            float p = Sc[q][kt0 + k];
            #pragma unroll
            for (int i = 0; i < 4; ++i) o[i] += p * KVs[k][dB + i];
        }
        __syncthreads();
    }
    #pragma unroll
    for (int i = 0; i < 4; ++i)
        O[(size_t)(baseQ + q) * Dm + hh * 64 + dB + i] = o[i] * inv;
}

// ---------------------------------------------------------------------------
// Fused residual + LayerNorm: Out[t] = LN(X[t] + R[t]) * g + b. One block/token.
// ---------------------------------------------------------------------------
__global__ __launch_bounds__(256) void ln_residual_kernel(
    const float* __restrict__ X, const float* __restrict__ R,
    const float* __restrict__ g, const float* __restrict__ bta,
    float* __restrict__ Out)
{
    __shared__ float red[8];
    const int t = blockIdx.x, tid = threadIdx.x;
    float v[4];
    float s = 0.f;
    #pragma unroll
    for (int i = 0; i < 4; ++i) {
        int c = tid + i * 256;
        v[i] = X[(size_t)t * Dm + c] + R[(size_t)t * Dm + c];
        s += v[i];
    }
    #pragma unroll
    for (int off = 32; off; off >>= 1) s += __shfl_down(s, off);
    const int wid = tid >> 6;
    if ((tid & 63) == 0) red[wid] = s;
    __syncthreads();
    const float mean = (red[0] + red[1] + red[2] + red[3]) * (1.f / 1024.f);
    float s2 = 0.f;
    #pragma unroll
    for (int i = 0; i < 4; ++i) { float d = v[i] - mean; s2 += d * d; }
    #pragma unroll
    for (int off = 32; off; off >>= 1) s2 += __shfl_down(s2, off);
    if ((tid & 63) == 0) red[4 + wid] = s2;
    __syncthreads();
    const float var  = (red[4] + red[5] + red[6] + red[7]) * (1.f / 1024.f);
    const float rstd = rsqrtf(var + 1e-5f);
    #pragma unroll
    for (int i = 0; i < 4; ++i) {
        int c = tid + i * 256;
        Out[(size_t)t * Dm + c] = (v[i] - mean) * rstd * g[c] + bta[c];
    }
}

// ---------------------------------------------------------------------------
// MoE router: logits -> softmax -> top-2 -> gates; builds per-expert pair
// lists; accumulates load-balance stats. One wave per token.
// pair_id = 2*token + k (k=0 top-1 slot, k=1 top-2 slot).
// ---------------------------------------------------------------------------
__global__ __launch_bounds__(64) void router_kernel(
    const float* __restrict__ X, const float* __restrict__ rw,
    const float* __restrict__ rb, float* __restrict__ gatep,
    int* __restrict__ elist, int* __restrict__ ecnt,
    float* __restrict__ impf, float* __restrict__ cntf)
{
    const int t = blockIdx.x, lane = threadIdx.x;
    float l[NE];
    #pragma unroll
    for (int e = 0; e < NE; ++e) l[e] = 0.f;
    for (int d = lane; d < Dm; d += 64) {
        float x = X[(size_t)t * Dm + d];
        #pragma unroll
        for (int e = 0; e < NE; ++e) l[e] += x * rw[d * NE + e];
    }
    #pragma unroll
    for (int e = 0; e < NE; ++e) {
        float vv = l[e];
        #pragma unroll
        for (int off = 32; off; off >>= 1) vv += __shfl_down(vv, off);
        l[e] = vv;
    }
    if (lane == 0) {
        float mx = -1e30f;
        #pragma unroll
        for (int e = 0; e < NE; ++e) { l[e] += rb[e]; mx = fmaxf(mx, l[e]); }
        float p[NE];
        float sum = 0.f;
        #pragma unroll
        for (int e = 0; e < NE; ++e) { p[e] = expf(l[e] - mx); sum += p[e]; }
        const float inv = 1.f / sum;
        int e0 = 0, e1 = 0;
        float v0 = -1.f, v1 = -1.f;
        #pragma unroll
        for (int e = 0; e < NE; ++e) {
            float pe = p[e] * inv;
            atomicAdd(&impf[e], pe);
            if (pe > v0)      { v1 = v0; e1 = e0; v0 = pe; e0 = e; }
            else if (pe > v1) { v1 = pe; e1 = e; }
        }
        const float gs = 1.f / (v0 + v1);
        atomicAdd(&cntf[e0], 1.f);
        atomicAdd(&cntf[e1], 1.f);
        int p0 = atomicAdd(&ecnt[e0], 1);
        elist[e0 * Nt + p0] = 2 * t;
        int p1 = atomicAdd(&ecnt[e1], 1);
        elist[e1 * Nt + p1] = 2 * t + 1;
        gatep[2 * t]     = v0 * gs;
        gatep[2 * t + 1] = v1 * gs;
    }
}

__global__ void init_kernel(int* ecnt, float* impf, float* cntf)
{
    int i = threadIdx.x;
    if (i < NE) { ecnt[i] = 0; impf[i] = 0.f; cntf[i] = 0.f; }
}

__global__ void lb_kernel(const float* __restrict__ impf,
                          const float* __restrict__ cntf,
                          float* __restrict__ out)
{
    if (threadIdx.x == 0) {
        float s = 0.f;
        for (int e = 0; e < NE; ++e) s += cntf[e] * impf[e];
        // lb = E * sum_e (cnt/(N*K)) * (imp/N)
        out[0] = (float)NE * s / ((float)Nt * 2.f * (float)Nt);
    }
}

// ---------------------------------------------------------------------------
// Expert FFN pass 1: H[pid] = relu(X[token(pid)] @ w1[e] + b1[e]).
// Rows gathered from elist; grid (Ff/64, Nt/64, NE).
// ---------------------------------------------------------------------------
__global__ __launch_bounds__(256) void moe_ffn1(
    const float* __restrict__ X, const float* __restrict__ w1,
    const float* __restrict__ b1, float* __restrict__ Hb,
    const int* __restrict__ elist, const int* __restrict__ ecnt)
{
    const int e = blockIdx.z;
    const int cnt = ecnt[e];
    const int m0 = blockIdx.y * 64;
    if (m0 >= cnt) return;
    const int n0 = blockIdx.x * 64;
    __shared__ float As[64][17];
    __shared__ float Ws[16][65];
    __shared__ int ppid[64];
    __shared__ int prow[64];
    const int tidx = threadIdx.x;
    if (tidx < 64) {
        int gr = m0 + tidx;
        if (gr < cnt) {
            int pid = elist[e * Nt + gr];
            ppid[tidx] = pid;
            prow[tidx] = pid >> 1;
        } else { ppid[tidx] = -1; prow[tidx] = -1; }
    }
    __syncthreads();
    const float* W = w1 + (size_t)e * Dm * Ff;
    const int tx = tidx & 15, ty = tidx >> 4;
    float acc[4][4] = {};
    for (int k0 = 0; k0 < Dm; k0 += 16) {
        #pragma unroll
        for (int i = tidx; i < 64 * 16; i += 256) {
            int r = i >> 4, c = i & 15;
            int row = prow[r];
            As[r][c] = (row >= 0) ? X[(size_t)row * Dm + k0 + c] : 0.f;
        }
        #pragma unroll
        for (int i = tidx; i < 16 * 64; i += 256) {
            int r = i >> 6, c = i & 63;
            Ws[r][c] = W[(size_t)(k0 + r) * Ff + n0 + c];
        }
        __syncthreads();
        #pragma unroll
        for (int kk = 0; kk < 16; ++kk) {
            float a[4], b[4];
            #pragma unroll
            for (int i = 0; i < 4; ++i) a[i] = As[ty * 4 + i][kk];
            #pragma unroll
            for (int j = 0; j < 4; ++j) b[j] = Ws[kk][tx * 4 + j];
            #pragma unroll
            for (int i = 0; i < 4; ++i)
                #pragma unroll
                for (int j = 0; j < 4; ++j)
                    acc[i][j] += a[i] * b[j];
        }
        __syncthreads();
    }
    #pragma unroll
    for (int i = 0; i < 4; ++i) {
        int pid = ppid[ty * 4 + i];
        if (pid < 0) continue;
        #pragma unroll
        for (int j = 0; j < 4; ++j) {
            int c = n0 + tx * 4 + j;
            float vv = acc[i][j] + b1[e * Ff + c];
            Hb[(size_t)pid * Ff + c] = fmaxf(vv, 0.f);
        }
    }
}

// ---------------------------------------------------------------------------
// Expert FFN pass 2: Y[pid] = H[pid] @ w2[e] + b2[e]. Grid (Dm/64, Nt/64, NE).
// ---------------------------------------------------------------------------
__global__ __launch_bounds__(256) void moe_ffn2(
    const float* __restrict__ Hb, const float* __restrict__ w2,
    const float* __restrict__ b2, float* __restrict__ Y,
    const int* __restrict__ elist, const int* __restrict__ ecnt)
{
    const int e = blockIdx.z;
    const int cnt = ecnt[e];
    const int m0 = blockIdx.y * 64;
    if (m0 >= cnt) return;
    const int n0 = blockIdx.x * 64;
    __shared__ float As[64][17];
    __shared__ float Ws[16][65];
    __shared__ int ppid[64];
    const int tidx = threadIdx.x;
    if (tidx < 64) {
        int gr = m0 + tidx;
        ppid[tidx] = (gr < cnt) ? elist[e * Nt + gr] : -1;
    }
    __syncthreads();
    const float* W = w2 + (size_t)e * Ff * Dm;
    const int tx = tidx & 15, ty = tidx >> 4;
    float acc[4][4] = {};
    for (int k0 = 0; k0 < Ff; k0 += 16) {
        #pragma unroll
        for (int i = tidx; i < 64 * 16; i += 256) {
            int r = i >> 4, c = i & 15;
            int pid = ppid[r];
            As[r][c] = (pid >= 0) ? Hb[(size_t)pid * Ff + k0 + c] : 0.f;
        }
        #pragma unroll
        for (int i = tidx; i < 16 * 64; i += 256) {
            int r = i >> 6, c = i & 63;
            Ws[r][c] = W[(size_t)(k0 + r) * Dm + n0 + c];
        }
        __syncthreads();
        #pragma unroll
        for (int kk = 0; kk < 16; ++kk) {
            float a[4], b[4];
            #pragma unroll
            for (int i = 0; i < 4; ++i) a[i] = As[ty * 4 + i][kk];
            #pragma unroll
            for (int j = 0; j < 4; ++j) b[j] = Ws[kk][tx * 4 + j];
            #pragma unroll
            for (int i = 0; i < 4; ++i)
                #pragma unroll
                for (int j = 0; j < 4; ++j)
                    acc[i][j] += a[i] * b[j];
        }
        __syncthreads();
    }
    #pragma unroll
    for (int i = 0; i < 4; ++i) {
        int pid = ppid[ty * 4 + i];
        if (pid < 0) continue;
        #pragma unroll
        for (int j = 0; j < 4; ++j) {
            int c = n0 + tx * 4 + j;
            Y[(size_t)pid * Dm + c] = acc[i][j] + b2[e * Dm + c];
        }
    }
}

// out[t] = g0 * Y[2t] + g1 * Y[2t+1]
__global__ __launch_bounds__(256) void moe_combine(
    const float* __restrict__ Y, const float* __restrict__ gatep,
    float* __restrict__ Out)
{
    int i = blockIdx.x * 256 + threadIdx.x;
    int t = i >> 10, c = i & 1023;
    Out[i] = gatep[2 * t] * Y[(size_t)(2 * t) * Dm + c]
           + gatep[2 * t + 1] * Y[(size_t)(2 * t + 1) * Dm + c];
}

// ---------------------------------------------------------------------------
extern "C" void kernel_launch(void* const* d_in, const int* in_sizes, int n_in,
                              void* d_out, int out_size, void* d_ws, size_t ws_size,
                              hipStream_t stream)
{
    const float* tgt   = (const float*)d_in[0];
    const float* memry = (const float*)d_in[1];
    const float* sa_wq = (const float*)d_in[2];
    const float* sa_wk = (const float*)d_in[3];
    const float* sa_wv = (const float*)d_in[4];
    const float* sa_wo = (const float*)d_in[5];
    const float* ca_wq = (const float*)d_in[6];
    const float* ca_wk = (const float*)d_in[7];
    const float* ca_wv = (const float*)d_in[8];
    const float* ca_wo = (const float*)d_in[9];
    const float* sa_bq = (const float*)d_in[10];
    const float* sa_bk = (const float*)d_in[11];
    const float* sa_bv = (const float*)d_in[12];
    const float* sa_bo = (const float*)d_in[13];
    const float* ca_bq = (const float*)d_in[14];
    const float* ca_bk = (const float*)d_in[15];
    const float* ca_bv = (const float*)d_in[16];
    const float* ca_bo = (const float*)d_in[17];
    const float* ln1_g = (const float*)d_in[18];
    const float* ln2_g = (const float*)d_in[19];
    const float* ln3_g = (const float*)d_in[20];
    const float* ln1_b = (const float*)d_in[21];
    const float* ln2_b = (const float*)d_in[22];
    const float* ln3_b = (const float*)d_in[23];
    const float* rw    = (const float*)d_in[24];
    const float* rb    = (const float*)d_in[25];
    const float* w1    = (const float*)d_in[26];
    const float* b1    = (const float*)d_in[27];
    const float* w2    = (const float*)d_in[28];
    const float* b2    = (const float*)d_in[29];

    float* ws = (float*)d_ws;
    const size_t ND = (size_t)Nt * Dm;
    float* q    = ws;                 // N*D
    float* kbuf = ws + ND;            // N*D
    float* vbuf = ws + 2 * ND;        // N*D
    float* attn = ws + 3 * ND;        // N*D
    float* hbuf = ws;                 // 2*Nt*Ff = 4*ND, aliases q..attn (dead by then)
    float* t2   = ws + 4 * ND;        // N*D
    float* tb   = ws + 5 * ND;        // N*D
    float* ybuf = ws + 6 * ND;        // 2*N*D
    float* gatep = ws + 8 * ND;       // 2*Nt
    int*   elist = (int*)(gatep + 2 * Nt);  // NE*Nt
    int*   ecnt  = elist + NE * Nt;         // NE
    float* impf  = (float*)(ecnt + NE);     // NE
    float* cntf  = impf + NE;               // NE
    float* outp  = (float*)d_out;

    dim3 blk(256);
    dim3 gemmGridD(Dm / 64, Nt / 64);       // Nc = 1024 GEMMs
    dim3 attnGrid(Tn / 16, NH, Bn);

    // ---- self-attention ----
    gemm_bias_kernel<<<gemmGridD, blk, 0, stream>>>(tgt, sa_wq, sa_bq, q,    Nt, Dm, Dm);
    gemm_bias_kernel<<<gemmGridD, blk, 0, stream>>>(tgt, sa_wk, sa_bk, kbuf, Nt, Dm, Dm);
    gemm_bias_kernel<<<gemmGridD, blk, 0, stream>>>(tgt, sa_wv, sa_bv, vbuf, Nt, Dm, Dm);
    attention_kernel<<<attnGrid, blk, 0, stream>>>(q, kbuf, vbuf, attn);
    gemm_bias_kernel<<<gemmGridD, blk, 0, stream>>>(attn, sa_wo, sa_bo, t2,  Nt, Dm, Dm);
    ln_residual_kernel<<<Nt, blk, 0, stream>>>(tgt, t2, ln1_g, ln1_b, tb);

    // ---- cross-attention ----
    gemm_bias_kernel<<<gemmGridD, blk, 0, stream>>>(tb,    ca_wq, ca_bq, q,    Nt, Dm, Dm);
    gemm_bias_kernel<<<gemmGridD, blk, 0, stream>>>(memry, ca_wk, ca_bk, kbuf, Nt, Dm, Dm);
    gemm_bias_kernel<<<gemmGridD, blk, 0, stream>>>(memry, ca_wv, ca_bv, vbuf, Nt, Dm, Dm);
    attention_kernel<<<attnGrid, blk, 0, stream>>>(q, kbuf, vbuf, attn);
    gemm_bias_kernel<<<gemmGridD, blk, 0, stream>>>(attn, ca_wo, ca_bo, t2,   Nt, Dm, Dm);
    ln_residual_kernel<<<Nt, blk, 0, stream>>>(tb, t2, ln2_g, ln2_b, tb);

    // ---- MoE (sparse: only top-2 pairs computed) ----
    init_kernel<<<1, 64, 0, stream>>>(ecnt, impf, cntf);
    router_kernel<<<Nt, 64, 0, stream>>>(tb, rw, rb, gatep, elist, ecnt, impf, cntf);
    moe_ffn1<<<dim3(Ff / 64, Nt / 64, NE), blk, 0, stream>>>(tb, w1, b1, hbuf, elist, ecnt);
    moe_ffn2<<<dim3(Dm / 64, Nt / 64, NE), blk, 0, stream>>>(hbuf, w2, b2, ybuf, elist, ecnt);
    moe_combine<<<(Nt * Dm) / 256, blk, 0, stream>>>(ybuf, gatep, t2);
    ln_residual_kernel<<<Nt, blk, 0, stream>>>(tb, t2, ln3_g, ln3_b, outp);
    lb_kernel<<<1, 64, 0, stream>>>(impf, cntf, outp + ND);
}

// Round 3
// 1143.692 us; speedup vs baseline: 3.1712x; 3.1712x over previous
//
#include <hip/hip_runtime.h>

// Problem constants
constexpr int Dm = 1024;
constexpr int NH = 16;
constexpr int Ff = 2048;
constexpr int NE = 8;
constexpr int Bn = 4;
constexpr int Tn = 512;
constexpr int Nt = 2048;   // total tokens

typedef float  f32x4  __attribute__((ext_vector_type(4)));
typedef __bf16 bf16x8 __attribute__((ext_vector_type(8)));
typedef unsigned short u16x8 __attribute__((ext_vector_type(8)));

// fp32 -> bf16 round-to-nearest-even
__device__ inline unsigned short f2bf(float f) {
    unsigned u = __builtin_bit_cast(unsigned, f);
    u += 0x7FFFu + ((u >> 16) & 1u);
    return (unsigned short)(u >> 16);
}
__device__ inline float bf2f(unsigned short h) {
    unsigned u = (unsigned)h << 16;
    return __builtin_bit_cast(float, u);
}
// split x = hi + lo (hi,lo bf16; residual ~2^-18 relative)
__device__ inline void splitbf(float x, unsigned short& hi, unsigned short& lo) {
    hi = f2bf(x);
    lo = f2bf(x - bf2f(hi));
}
__device__ inline bf16x8 ld_frag(const unsigned short* p) {
    return __builtin_bit_cast(bf16x8, *(const u16x8*)p);
}

// ---------------------------------------------------------------------------
// Split-bf16 MFMA GEMM: C = act(A @ W + bias), fp32 in/out, fp32-grade
// precision via 3-term MFMA (AhBh + AhBl + AlBh). Tile 128x128x32, 4 waves.
// W as up-to-3 1024-col segments. Row gather modes: 0 dense, 1 ffn1, 2 ffn2.
// ---------------------------------------------------------------------------
template <int SPLIT>
__global__ __launch_bounds__(256) void gemm_bf16_kernel(
    const float* __restrict__ A, int lda,
    const float* __restrict__ W0, const float* __restrict__ W1,
    const float* __restrict__ W2, int ldw, size_t weStride,
    const float* __restrict__ B0, const float* __restrict__ B1,
    const float* __restrict__ B2, size_t beStride,
    float* __restrict__ C, int ldc,
    int Mparam, int K,
    const int* __restrict__ lst, int lstStride, const int* __restrict__ cnt,
    int mode, int relu)
{
    __shared__ __align__(16) unsigned short AsH[128 * 40];
    __shared__ __align__(16) unsigned short WsH[128 * 40];
    __shared__ __align__(16) unsigned short AsL[SPLIT ? 128 * 40 : 1];
    __shared__ __align__(16) unsigned short WsL[SPLIT ? 128 * 40 : 1];
    __shared__ int inIdx[128];
    __shared__ int outIdx[128];

    const int e = blockIdx.z;
    const int M = (mode == 0) ? Mparam : cnt[e];
    const int m0 = blockIdx.y * 128;
    if (m0 >= M) return;
    const int n0 = blockIdx.x * 128;
    const int seg = n0 >> 10;
    const float* W = ((seg == 0) ? W0 : (seg == 1) ? W1 : W2) + (size_t)e * weStride;
    const float* bias = ((seg == 0) ? B0 : (seg == 1) ? B1 : B2) + (size_t)e * beStride;
    const int nseg = n0 & 1023;
    const int tid = threadIdx.x;

    if (tid < 128) {
        int g = m0 + tid;
        bool valid = g < M;
        int gi, go;
        if (mode == 0) { gi = valid ? g : (M - 1); go = valid ? g : -1; }
        else {
            int pid = lst[(size_t)e * lstStride + (valid ? g : 0)];
            gi = (mode == 1) ? (pid >> 1) : pid;
            go = valid ? pid : -1;
        }
        inIdx[tid] = gi;
        outIdx[tid] = go;
    }
    __syncthreads();

    const int ar = tid >> 1, ahalf = tid & 1;                  // A: 2 thr/row
    const int bn = (tid & 63) * 2, bko = ((tid >> 6) & 3) * 8; // B: 2 n, 8 k
    const float* aBase = A + (size_t)inIdx[ar] * lda + ahalf * 16;
    const float* wBase = W + (size_t)bko * ldw + nseg + bn;

    const int lane = tid & 63, wv = tid >> 6;
    const int wy = (wv >> 1) * 64, wx = (wv & 1) * 64;
    const int l15 = lane & 15, quad = lane >> 4;

    f32x4 acc[4][4];
    #pragma unroll
    for (int i = 0; i < 4; ++i)
        #pragma unroll
        for (int j = 0; j < 4; ++j) acc[i][j] = (f32x4)0.f;

    for (int k0 = 0; k0 < K; k0 += 32) {
        // ---- stage A tile [m][k] (hi/lo) ----
        {
            const float* ap = aBase + k0;
            float v[16];
            *(float4*)&v[0]  = *(const float4*)(ap);
            *(float4*)&v[4]  = *(const float4*)(ap + 4);
            *(float4*)&v[8]  = *(const float4*)(ap + 8);
            *(float4*)&v[12] = *(const float4*)(ap + 12);
            u16x8 h0, h1, l0, l1;
            #pragma unroll
            for (int i = 0; i < 8; ++i) {
                unsigned short hh, ll;
                splitbf(v[i], hh, ll); h0[i] = hh; l0[i] = ll;
                splitbf(v[8 + i], hh, ll); h1[i] = hh; l1[i] = ll;
            }
            *(u16x8*)&AsH[ar * 40 + ahalf * 16]     = h0;
            *(u16x8*)&AsH[ar * 40 + ahalf * 16 + 8] = h1;
            if (SPLIT) {
                *(u16x8*)&AsL[ar * 40 + ahalf * 16]     = l0;
                *(u16x8*)&AsL[ar * 40 + ahalf * 16 + 8] = l1;
            }
        }
        // ---- stage W tile transposed [n][k] (hi/lo) ----
        {
            const float* wp = wBase + (size_t)k0 * ldw;
            float2 wr[8];
            #pragma unroll
            for (int j = 0; j < 8; ++j) wr[j] = *(const float2*)(wp + (size_t)j * ldw);
            u16x8 h0, h1, l0, l1;
            #pragma unroll
            for (int j = 0; j < 8; ++j) {
                unsigned short hh, ll;
                splitbf(wr[j].x, hh, ll); h0[j] = hh; l0[j] = ll;
                splitbf(wr[j].y, hh, ll); h1[j] = hh; l1[j] = ll;
            }
            *(u16x8*)&WsH[bn * 40 + bko]       = h0;
            *(u16x8*)&WsH[(bn + 1) * 40 + bko] = h1;
            if (SPLIT) {
                *(u16x8*)&WsL[bn * 40 + bko]       = l0;
                *(u16x8*)&WsL[(bn + 1) * 40 + bko] = l1;
            }
        }
        __syncthreads();
        // ---- fragments + MFMA ----
        bf16x8 ah[4], bh[4], al[4], bl[4];
        #pragma unroll
        for (int mi = 0; mi < 4; ++mi)
            ah[mi] = ld_frag(&AsH[(wy + mi * 16 + l15) * 40 + quad * 8]);
        #pragma unroll
        for (int ni = 0; ni < 4; ++ni)
            bh[ni] = ld_frag(&WsH[(wx + ni * 16 + l15) * 40 + quad * 8]);
        if (SPLIT) {
            #pragma unroll
            for (int mi = 0; mi < 4; ++mi)
                al[mi] = ld_frag(&AsL[(wy + mi * 16 + l15) * 40 + quad * 8]);
            #pragma unroll
            for (int ni = 0; ni < 4; ++ni)
                bl[ni] = ld_frag(&WsL[(wx + ni * 16 + l15) * 40 + quad * 8]);
        }
        #pragma unroll
        for (int mi = 0; mi < 4; ++mi)
            #pragma unroll
            for (int ni = 0; ni < 4; ++ni) {
                acc[mi][ni] = __builtin_amdgcn_mfma_f32_16x16x32_bf16(
                    ah[mi], bh[ni], acc[mi][ni], 0, 0, 0);
                if (SPLIT) {
                    acc[mi][ni] = __builtin_amdgcn_mfma_f32_16x16x32_bf16(
                        ah[mi], bl[ni], acc[mi][ni], 0, 0, 0);
                    acc[mi][ni] = __builtin_amdgcn_mfma_f32_16x16x32_bf16(
                        al[mi], bh[ni], acc[mi][ni], 0, 0, 0);
                }
            }
        __syncthreads();
    }

    // ---- epilogue ----
    #pragma unroll
    for (int mi = 0; mi < 4; ++mi) {
        #pragma unroll
        for (int r = 0; r < 4; ++r) {
            int rl = wy + mi * 16 + quad * 4 + r;
            int orow = outIdx[rl];
            if (orow < 0) continue;
            #pragma unroll
            for (int ni = 0; ni < 4; ++ni) {
                int col = n0 + wx + ni * 16 + l15;
                float val = acc[mi][ni][r] + bias[col & 1023];
                if (relu) val = fmaxf(val, 0.f);
                C[(size_t)orow * ldc + col] = val;
            }
        }
    }
}

// ---------------------------------------------------------------------------
// Split-bf16 flash attention. Block = 64 Q rows x (b,h); 4 waves x 16 Q rows.
// ---------------------------------------------------------------------------
__global__ __launch_bounds__(256) void attn_kernel(
    const float* __restrict__ Qp, int qld,
    const float* __restrict__ Kp, int kld, int kOff,
    const float* __restrict__ Vp, int vld, int vOff,
    float* __restrict__ O)
{
    __shared__ __align__(16) unsigned short KtH[64 * 72], KtL[64 * 72];
    __shared__ __align__(16) unsigned short VtH[64 * 72], VtL[64 * 72];
    __shared__ __align__(16) unsigned short PtH[4][16 * 72], PtL[4][16 * 72];

    const int tid = threadIdx.x, lane = tid & 63, wv = tid >> 6;
    const int quad = lane >> 4, l15 = lane & 15;
    const int b = blockIdx.z, h = blockIdx.y, q0 = blockIdx.x * 64;
    const int bT = b * Tn;

    // preload Q fragments hi/lo (2 k-halves of d=64)
    bf16x8 aqh[2], aql[2];
    {
        const float* qp = Qp + (size_t)(bT + q0 + wv * 16 + l15) * qld + h * 64;
        #pragma unroll
        for (int s = 0; s < 2; ++s) {
            float v[8];
            *(float4*)&v[0] = *(const float4*)(qp + s * 32 + quad * 8);
            *(float4*)&v[4] = *(const float4*)(qp + s * 32 + quad * 8 + 4);
            u16x8 th, tl;
            #pragma unroll
            for (int i = 0; i < 8; ++i) {
                unsigned short hh, ll;
                splitbf(v[i], hh, ll); th[i] = hh; tl[i] = ll;
            }
            aqh[s] = __builtin_bit_cast(bf16x8, th);
            aql[s] = __builtin_bit_cast(bf16x8, tl);
        }
    }

    f32x4 oacc[4];
    #pragma unroll
    for (int i = 0; i < 4; ++i) oacc[i] = (f32x4)0.f;
    float mrow[4] = {-1e30f, -1e30f, -1e30f, -1e30f};
    float lrow[4] = {0.f, 0.f, 0.f, 0.f};

    const int rr = tid >> 2, cc = tid & 3;

    for (int kt0 = 0; kt0 < Tn; kt0 += 64) {
        // ---- stage K [kt][d] hi/lo, V transposed [d][kt] hi/lo ----
        {
            const float* kr = Kp + (size_t)(bT + kt0 + rr) * kld + kOff + h * 64 + cc * 16;
            float v[16];
            *(float4*)&v[0]  = *(const float4*)(kr);
            *(float4*)&v[4]  = *(const float4*)(kr + 4);
            *(float4*)&v[8]  = *(const float4*)(kr + 8);
            *(float4*)&v[12] = *(const float4*)(kr + 12);
            u16x8 h0, h1, l0, l1;
            #pragma unroll
            for (int i = 0; i < 8; ++i) {
                unsigned short hh, ll;
                splitbf(v[i], hh, ll); h0[i] = hh; l0[i] = ll;
                splitbf(v[8 + i], hh, ll); h1[i] = hh; l1[i] = ll;
            }
            *(u16x8*)&KtH[rr * 72 + cc * 16]     = h0;
            *(u16x8*)&KtH[rr * 72 + cc * 16 + 8] = h1;
            *(u16x8*)&KtL[rr * 72 + cc * 16]     = l0;
            *(u16x8*)&KtL[rr * 72 + cc * 16 + 8] = l1;

            const float* vr = Vp + (size_t)(bT + kt0 + rr) * vld + vOff + h * 64 + cc * 16;
            float fv[16];
            *(float4*)&fv[0]  = *(const float4*)(vr);
            *(float4*)&fv[4]  = *(const float4*)(vr + 4);
            *(float4*)&fv[8]  = *(const float4*)(vr + 8);
            *(float4*)&fv[12] = *(const float4*)(vr + 12);
            #pragma unroll
            for (int i = 0; i < 16; ++i) {
                unsigned short hh, ll;
                splitbf(fv[i], hh, ll);
                VtH[(cc * 16 + i) * 72 + rr] = hh;
                VtL[(cc * 16 + i) * 72 + rr] = ll;
            }
        }
        __syncthreads();

        // ---- S = (Q K^T) * 0.125, split 3-term ----
        f32x4 sacc[4];
        #pragma unroll
        for (int nt = 0; nt < 4; ++nt) {
            sacc[nt] = (f32x4)0.f;
            #pragma unroll
            for (int s = 0; s < 2; ++s) {
                bf16x8 bkh = ld_frag(&KtH[(nt * 16 + l15) * 72 + s * 32 + quad * 8]);
                bf16x8 bkl = ld_frag(&KtL[(nt * 16 + l15) * 72 + s * 32 + quad * 8]);
                sacc[nt] = __builtin_amdgcn_mfma_f32_16x16x32_bf16(aqh[s], bkh, sacc[nt], 0, 0, 0);
                sacc[nt] = __builtin_amdgcn_mfma_f32_16x16x32_bf16(aqh[s], bkl, sacc[nt], 0, 0, 0);
                sacc[nt] = __builtin_amdgcn_mfma_f32_16x16x32_bf16(aql[s], bkh, sacc[nt], 0, 0, 0);
            }
        }
        #pragma unroll
        for (int nt = 0; nt < 4; ++nt)
            #pragma unroll
            for (int r = 0; r < 4; ++r) sacc[nt][r] *= 0.125f;

        // ---- online softmax ----
        float alpha[4], mnew[4];
        #pragma unroll
        for (int r = 0; r < 4; ++r) {
            float mx = fmaxf(fmaxf(sacc[0][r], sacc[1][r]), fmaxf(sacc[2][r], sacc[3][r]));
            #pragma unroll
            for (int msk = 1; msk < 16; msk <<= 1) mx = fmaxf(mx, __shfl_xor(mx, msk));
            mnew[r] = fmaxf(mrow[r], mx);
            alpha[r] = __expf(mrow[r] - mnew[r]);
            mrow[r] = mnew[r];
        }
        float rs[4] = {0.f, 0.f, 0.f, 0.f};
        #pragma unroll
        for (int nt = 0; nt < 4; ++nt)
            #pragma unroll
            for (int r = 0; r < 4; ++r) {
                float p = __expf(sacc[nt][r] - mnew[r]);
                sacc[nt][r] = p;
                rs[r] += p;
            }
        #pragma unroll
        for (int r = 0; r < 4; ++r) {
            #pragma unroll
            for (int msk = 1; msk < 16; msk <<= 1) rs[r] += __shfl_xor(rs[r], msk);
            lrow[r] = lrow[r] * alpha[r] + rs[r];
        }
        #pragma unroll
        for (int ni = 0; ni < 4; ++ni)
            #pragma unroll
            for (int r = 0; r < 4; ++r) oacc[ni][r] *= alpha[r];

        // ---- P: C-layout -> A-layout via per-wave LDS (hi/lo) ----
        #pragma unroll
        for (int nt = 0; nt < 4; ++nt)
            #pragma unroll
            for (int r = 0; r < 4; ++r) {
                unsigned short hh, ll;
                splitbf(sacc[nt][r], hh, ll);
                PtH[wv][(quad * 4 + r) * 72 + nt * 16 + l15] = hh;
                PtL[wv][(quad * 4 + r) * 72 + nt * 16 + l15] = ll;
            }
        asm volatile("s_waitcnt lgkmcnt(0)" ::: "memory");

        // ---- O += P @ V, split 3-term ----
        #pragma unroll
        for (int s = 0; s < 2; ++s) {
            bf16x8 aph = ld_frag(&PtH[wv][l15 * 72 + s * 32 + quad * 8]);
            bf16x8 apl = ld_frag(&PtL[wv][l15 * 72 + s * 32 + quad * 8]);
            #pragma unroll
            for (int ni = 0; ni < 4; ++ni) {
                bf16x8 bvh = ld_frag(&VtH[(ni * 16 + l15) * 72 + s * 32 + quad * 8]);
                bf16x8 bvl = ld_frag(&VtL[(ni * 16 + l15) * 72 + s * 32 + quad * 8]);
                oacc[ni] = __builtin_amdgcn_mfma_f32_16x16x32_bf16(aph, bvh, oacc[ni], 0, 0, 0);
                oacc[ni] = __builtin_amdgcn_mfma_f32_16x16x32_bf16(aph, bvl, oacc[ni], 0, 0, 0);
                oacc[ni] = __builtin_amdgcn_mfma_f32_16x16x32_bf16(apl, bvh, oacc[ni], 0, 0, 0);
            }
        }
        __syncthreads();
    }

    // ---- epilogue ----
    #pragma unroll
    for (int r = 0; r < 4; ++r) {
        float inv = 1.f / lrow[r];
        int orow = bT + q0 + wv * 16 + quad * 4 + r;
        #pragma unroll
        for (int ni = 0; ni < 4; ++ni) {
            int col = h * 64 + ni * 16 + l15;
            O[(size_t)orow * Dm + col] = oacc[ni][r] * inv;
        }
    }
}

// ---------------------------------------------------------------------------
// Fused residual + LayerNorm
// ---------------------------------------------------------------------------
__global__ __launch_bounds__(256) void ln_residual_kernel(
    const float* __restrict__ X, const float* __restrict__ R,
    const float* __restrict__ g, const float* __restrict__ bta,
    float* __restrict__ Out)
{
    __shared__ float red[8];
    const int t = blockIdx.x, tid = threadIdx.x;
    float v[4];
    float s = 0.f;
    #pragma unroll
    for (int i = 0; i < 4; ++i) {
        int c = tid + i * 256;
        v[i] = X[(size_t)t * Dm + c] + R[(size_t)t * Dm + c];
        s += v[i];
    }
    #pragma unroll
    for (int off = 32; off; off >>= 1) s += __shfl_down(s, off);
    const int wid = tid >> 6;
    if ((tid & 63) == 0) red[wid] = s;
    __syncthreads();
    const float mean = (red[0] + red[1] + red[2] + red[3]) * (1.f / 1024.f);
    float s2 = 0.f;
    #pragma unroll
    for (int i = 0; i < 4; ++i) { float d = v[i] - mean; s2 += d * d; }
    #pragma unroll
    for (int off = 32; off; off >>= 1) s2 += __shfl_down(s2, off);
    if ((tid & 63) == 0) red[4 + wid] = s2;
    __syncthreads();
    const float var  = (red[4] + red[5] + red[6] + red[7]) * (1.f / 1024.f);
    const float rstd = rsqrtf(var + 1e-5f);
    #pragma unroll
    for (int i = 0; i < 4; ++i) {
        int c = tid + i * 256;
        Out[(size_t)t * Dm + c] = (v[i] - mean) * rstd * g[c] + bta[c];
    }
}

// ---------------------------------------------------------------------------
// MoE router
// ---------------------------------------------------------------------------
__global__ __launch_bounds__(64) void router_kernel(
    const float* __restrict__ X, const float* __restrict__ rw,
    const float* __restrict__ rb, float* __restrict__ gatep,
    int* __restrict__ elist, int* __restrict__ ecnt,
    float* __restrict__ impf, float* __restrict__ cntf)
{
    const int t = blockIdx.x, lane = threadIdx.x;
    float l[NE];
    #pragma unroll
    for (int e = 0; e < NE; ++e) l[e] = 0.f;
    for (int d = lane; d < Dm; d += 64) {
        float x = X[(size_t)t * Dm + d];
        #pragma unroll
        for (int e = 0; e < NE; ++e) l[e] += x * rw[d * NE + e];
    }
    #pragma unroll
    for (int e = 0; e < NE; ++e) {
        float vv = l[e];
        #pragma unroll
        for (int off = 32; off; off >>= 1) vv += __shfl_down(vv, off);
        l[e] = vv;
    }
    if (lane == 0) {
        float mx = -1e30f;
        #pragma unroll
        for (int e = 0; e < NE; ++e) { l[e] += rb[e]; mx = fmaxf(mx, l[e]); }
        float p[NE];
        float sum = 0.f;
        #pragma unroll
        for (int e = 0; e < NE; ++e) { p[e] = expf(l[e] - mx); sum += p[e]; }
        const float inv = 1.f / sum;
        int e0 = 0, e1 = 0;
        float v0 = -1.f, v1 = -1.f;
        #pragma unroll
        for (int e = 0; e < NE; ++e) {
            float pe = p[e] * inv;
            atomicAdd(&impf[e], pe);
            if (pe > v0)      { v1 = v0; e1 = e0; v0 = pe; e0 = e; }
            else if (pe > v1) { v1 = pe; e1 = e; }
        }
        const float gs = 1.f / (v0 + v1);
        atomicAdd(&cntf[e0], 1.f);
        atomicAdd(&cntf[e1], 1.f);
        int p0 = atomicAdd(&ecnt[e0], 1);
        elist[e0 * Nt + p0] = 2 * t;
        int p1 = atomicAdd(&ecnt[e1], 1);
        elist[e1 * Nt + p1] = 2 * t + 1;
        gatep[2 * t]     = v0 * gs;
        gatep[2 * t + 1] = v1 * gs;
    }
}

__global__ void init_kernel(int* ecnt, float* impf, float* cntf)
{
    int i = threadIdx.x;
    if (i < NE) { ecnt[i] = 0; impf[i] = 0.f; cntf[i] = 0.f; }
}

__global__ void lb_kernel(const float* __restrict__ impf,
                          const float* __restrict__ cntf,
                          float* __restrict__ out)
{
    if (threadIdx.x == 0) {
        float s = 0.f;
        for (int e = 0; e < NE; ++e) s += cntf[e] * impf[e];
        out[0] = (float)NE * s / ((float)Nt * 2.f * (float)Nt);
    }
}

__global__ __launch_bounds__(256) void moe_combine(
    const float* __restrict__ Y, const float* __restrict__ gatep,
    float* __restrict__ Out)
{
    int i = blockIdx.x * 256 + threadIdx.x;
    int t = i >> 10, c = i & 1023;
    Out[i] = gatep[2 * t] * Y[(size_t)(2 * t) * Dm + c]
           + gatep[2 * t + 1] * Y[(size_t)(2 * t + 1) * Dm + c];
}

// ---------------------------------------------------------------------------
extern "C" void kernel_launch(void* const* d_in, const int* in_sizes, int n_in,
                              void* d_out, int out_size, void* d_ws, size_t ws_size,
                              hipStream_t stream)
{
    const float* tgt   = (const float*)d_in[0];
    const float* memry = (const float*)d_in[1];
    const float* sa_wq = (const float*)d_in[2];
    const float* sa_wk = (const float*)d_in[3];
    const float* sa_wv = (const float*)d_in[4];
    const float* sa_wo = (const float*)d_in[5];
    const float* ca_wq = (const float*)d_in[6];
    const float* ca_wk = (const float*)d_in[7];
    const float* ca_wv = (const float*)d_in[8];
    const float* ca_wo = (const float*)d_in[9];
    const float* sa_bq = (const float*)d_in[10];
    const float* sa_bk = (const float*)d_in[11];
    const float* sa_bv = (const float*)d_in[12];
    const float* sa_bo = (const float*)d_in[13];
    const float* ca_bq = (const float*)d_in[14];
    const float* ca_bk = (const float*)d_in[15];
    const float* ca_bv = (const float*)d_in[16];
    const float* ca_bo = (const float*)d_in[17];
    const float* ln1_g = (const float*)d_in[18];
    const float* ln2_g = (const float*)d_in[19];
    const float* ln3_g = (const float*)d_in[20];
    const float* ln1_b = (const float*)d_in[21];
    const float* ln2_b = (const float*)d_in[22];
    const float* ln3_b = (const float*)d_in[23];
    const float* rw    = (const float*)d_in[24];
    const float* rb    = (const float*)d_in[25];
    const float* w1    = (const float*)d_in[26];
    const float* b1    = (const float*)d_in[27];
    const float* w2    = (const float*)d_in[28];
    const float* b2    = (const float*)d_in[29];

    float* ws = (float*)d_ws;
    const size_t ND = (size_t)Nt * Dm;
    float* qkv  = ws;                         // 3*ND
    float* qc   = ws;
    float* kvc  = ws + ND;
    float* attnO = ws + 3 * ND;               // ND
    float* hbuf = ws;                         // 4*ND (aliases, dead by MoE)
    float* t2   = ws + 4 * ND;                // ND
    float* tb   = ws + 5 * ND;                // ND
    float* ybuf = ws + 6 * ND;                // 2*ND
    float* gatep = ws + 8 * ND;               // 2*Nt
    int*   elist = (int*)(gatep + 2 * Nt);    // NE*Nt
    int*   ecnt  = elist + NE * Nt;           // NE
    float* impf  = (float*)(ecnt + NE);       // NE
    float* cntf  = impf + NE;                 // NE
    float* outp  = (float*)d_out;

    dim3 blk(256);
    dim3 attnGrid(Tn / 64, NH, Bn);

    // ---- self-attention ----
    gemm_bf16_kernel<1><<<dim3(24, 16, 1), blk, 0, stream>>>(
        tgt, Dm, sa_wq, sa_wk, sa_wv, Dm, 0, sa_bq, sa_bk, sa_bv, 0,
        qkv, 3 * Dm, Nt, Dm, nullptr, 0, nullptr, 0, 0);
    attn_kernel<<<attnGrid, blk, 0, stream>>>(
        qkv, 3 * Dm, qkv, 3 * Dm, 1024, qkv, 3 * Dm, 2048, attnO);
    gemm_bf16_kernel<1><<<dim3(8, 16, 1), blk, 0, stream>>>(
        attnO, Dm, sa_wo, sa_wo, sa_wo, Dm, 0, sa_bo, sa_bo, sa_bo, 0,
        t2, Dm, Nt, Dm, nullptr, 0, nullptr, 0, 0);
    ln_residual_kernel<<<Nt, blk, 0, stream>>>(tgt, t2, ln1_g, ln1_b, tb);

    // ---- cross-attention ----
    gemm_bf16_kernel<1><<<dim3(8, 16, 1), blk, 0, stream>>>(
        tb, Dm, ca_wq, ca_wq, ca_wq, Dm, 0, ca_bq, ca_bq, ca_bq, 0,
        qc, Dm, Nt, Dm, nullptr, 0, nullptr, 0, 0);
    gemm_bf16_kernel<1><<<dim3(16, 16, 1), blk, 0, stream>>>(
        memry, Dm, ca_wk, ca_wv, ca_wv, Dm, 0, ca_bk, ca_bv, ca_bv, 0,
        kvc, 2 * Dm, Nt, Dm, nullptr, 0, nullptr, 0, 0);
    attn_kernel<<<attnGrid, blk, 0, stream>>>(
        qc, Dm, kvc, 2 * Dm, 0, kvc, 2 * Dm, 1024, attnO);
    gemm_bf16_kernel<1><<<dim3(8, 16, 1), blk, 0, stream>>>(
        attnO, Dm, ca_wo, ca_wo, ca_wo, Dm, 0, ca_bo, ca_bo, ca_bo, 0,
        t2, Dm, Nt, Dm, nullptr, 0, nullptr, 0, 0);
    ln_residual_kernel<<<Nt, blk, 0, stream>>>(tb, t2, ln2_g, ln2_b, tb);

    // ---- MoE ----
    init_kernel<<<1, 64, 0, stream>>>(ecnt, impf, cntf);
    router_kernel<<<Nt, 64, 0, stream>>>(tb, rw, rb, gatep, elist, ecnt, impf, cntf);
    gemm_bf16_kernel<1><<<dim3(16, 16, 8), blk, 0, stream>>>(
        tb, Dm, w1, w1 + 1024, w1 + 1024, Ff, (size_t)Dm * Ff, b1, b1 + 1024, b1 + 1024, Ff,
        hbuf, Ff, 0, Dm, elist, Nt, ecnt, 1, 1);
    gemm_bf16_kernel<1><<<dim3(8, 16, 8), blk, 0, stream>>>(
        hbuf, Ff, w2, w2, w2, Dm, (size_t)Ff * Dm, b2, b2, b2, Dm,
        ybuf, Dm, 0, Ff, elist, Nt, ecnt, 2, 0);
    moe_combine<<<(Nt * Dm) / 256, blk, 0, stream>>>(ybuf, gatep, t2);
    ln_residual_kernel<<<Nt, blk, 0, stream>>>(tb, t2, ln3_g, ln3_b, outp);
    lb_kernel<<<1, 64, 0, stream>>>(impf, cntf, outp + ND);
}

// Round 4
// 895.973 us; speedup vs baseline: 4.0480x; 1.2765x over previous
//
#include <hip/hip_runtime.h>

// Problem constants
constexpr int Dm = 1024;
constexpr int NH = 16;
constexpr int Ff = 2048;
constexpr int NE = 8;
constexpr int Bn = 4;
constexpr int Tn = 512;
constexpr int Nt = 2048;   // total tokens

typedef float  f32x4  __attribute__((ext_vector_type(4)));
typedef __bf16 bf16x8 __attribute__((ext_vector_type(8)));
typedef unsigned short u16x8 __attribute__((ext_vector_type(8)));

// fp32 -> bf16 round-to-nearest-even
__device__ inline unsigned short f2bf(float f) {
    unsigned u = __builtin_bit_cast(unsigned, f);
    u += 0x7FFFu + ((u >> 16) & 1u);
    return (unsigned short)(u >> 16);
}
__device__ inline float bf2f(unsigned short h) {
    unsigned u = (unsigned)h << 16;
    return __builtin_bit_cast(float, u);
}
// split x = hi + lo (hi,lo bf16; residual ~2^-18 relative)
__device__ inline void splitbf(float x, unsigned short& hi, unsigned short& lo) {
    hi = f2bf(x);
    lo = f2bf(x - bf2f(hi));
}
__device__ inline bf16x8 ld_frag(const unsigned short* p) {
    return __builtin_bit_cast(bf16x8, *(const u16x8*)p);
}

// ---------------------------------------------------------------------------
// Split-bf16 MFMA GEMM: C = act(A @ W + bias), fp32 in/out, fp32-grade
// precision via 3-term MFMA (AhBh + AhBl + AlBh). Tile 128x128x32, 4 waves.
// W as up-to-3 1024-col segments. Row gather modes: 0 dense, 1 ffn1, 2 ffn2.
// ---------------------------------------------------------------------------
template <int SPLIT>
__global__ __launch_bounds__(256) void gemm_bf16_kernel(
    const float* __restrict__ A, int lda,
    const float* __restrict__ W0, const float* __restrict__ W1,
    const float* __restrict__ W2, int ldw, size_t weStride,
    const float* __restrict__ B0, const float* __restrict__ B1,
    const float* __restrict__ B2, size_t beStride,
    float* __restrict__ C, int ldc,
    int Mparam, int K,
    const int* __restrict__ lst, int lstStride, const int* __restrict__ cnt,
    int mode, int relu)
{
    __shared__ __align__(16) unsigned short AsH[128 * 40];
    __shared__ __align__(16) unsigned short WsH[128 * 40];
    __shared__ __align__(16) unsigned short AsL[SPLIT ? 128 * 40 : 1];
    __shared__ __align__(16) unsigned short WsL[SPLIT ? 128 * 40 : 1];
    __shared__ int inIdx[128];
    __shared__ int outIdx[128];

    const int e = blockIdx.z;
    const int M = (mode == 0) ? Mparam : cnt[e];
    const int m0 = blockIdx.y * 128;
    if (m0 >= M) return;
    const int n0 = blockIdx.x * 128;
    const int seg = n0 >> 10;
    const float* W = ((seg == 0) ? W0 : (seg == 1) ? W1 : W2) + (size_t)e * weStride;
    const float* bias = ((seg == 0) ? B0 : (seg == 1) ? B1 : B2) + (size_t)e * beStride;
    const int nseg = n0 & 1023;
    const int tid = threadIdx.x;

    if (tid < 128) {
        int g = m0 + tid;
        bool valid = g < M;
        int gi, go;
        if (mode == 0) { gi = valid ? g : (M - 1); go = valid ? g : -1; }
        else {
            int pid = lst[(size_t)e * lstStride + (valid ? g : 0)];
            gi = (mode == 1) ? (pid >> 1) : pid;
            go = valid ? pid : -1;
        }
        inIdx[tid] = gi;
        outIdx[tid] = go;
    }
    __syncthreads();

    const int ar = tid >> 1, ahalf = tid & 1;                  // A: 2 thr/row
    const int bn = (tid & 63) * 2, bko = ((tid >> 6) & 3) * 8; // B: 2 n, 8 k
    const float* aBase = A + (size_t)inIdx[ar] * lda + ahalf * 16;
    const float* wBase = W + (size_t)bko * ldw + nseg + bn;

    const int lane = tid & 63, wv = tid >> 6;
    const int wy = (wv >> 1) * 64, wx = (wv & 1) * 64;
    const int l15 = lane & 15, quad = lane >> 4;

    f32x4 acc[4][4];
    #pragma unroll
    for (int i = 0; i < 4; ++i)
        #pragma unroll
        for (int j = 0; j < 4; ++j) acc[i][j] = (f32x4)0.f;

    for (int k0 = 0; k0 < K; k0 += 32) {
        // ---- stage A tile [m][k] (hi/lo) ----
        {
            const float* ap = aBase + k0;
            float v[16];
            *(float4*)&v[0]  = *(const float4*)(ap);
            *(float4*)&v[4]  = *(const float4*)(ap + 4);
            *(float4*)&v[8]  = *(const float4*)(ap + 8);
            *(float4*)&v[12] = *(const float4*)(ap + 12);
            u16x8 h0, h1, l0, l1;
            #pragma unroll
            for (int i = 0; i < 8; ++i) {
                unsigned short hh, ll;
                splitbf(v[i], hh, ll); h0[i] = hh; l0[i] = ll;
                splitbf(v[8 + i], hh, ll); h1[i] = hh; l1[i] = ll;
            }
            *(u16x8*)&AsH[ar * 40 + ahalf * 16]     = h0;
            *(u16x8*)&AsH[ar * 40 + ahalf * 16 + 8] = h1;
            if (SPLIT) {
                *(u16x8*)&AsL[ar * 40 + ahalf * 16]     = l0;
                *(u16x8*)&AsL[ar * 40 + ahalf * 16 + 8] = l1;
            }
        }
        // ---- stage W tile transposed [n][k] (hi/lo) ----
        {
            const float* wp = wBase + (size_t)k0 * ldw;
            float2 wr[8];
            #pragma unroll
            for (int j = 0; j < 8; ++j) wr[j] = *(const float2*)(wp + (size_t)j * ldw);
            u16x8 h0, h1, l0, l1;
            #pragma unroll
            for (int j = 0; j < 8; ++j) {
                unsigned short hh, ll;
                splitbf(wr[j].x, hh, ll); h0[j] = hh; l0[j] = ll;
                splitbf(wr[j].y, hh, ll); h1[j] = hh; l1[j] = ll;
            }
            *(u16x8*)&WsH[bn * 40 + bko]       = h0;
            *(u16x8*)&WsH[(bn + 1) * 40 + bko] = h1;
            if (SPLIT) {
                *(u16x8*)&WsL[bn * 40 + bko]       = l0;
                *(u16x8*)&WsL[(bn + 1) * 40 + bko] = l1;
            }
        }
        __syncthreads();
        // ---- fragments + MFMA ----
        bf16x8 ah[4], bh[4], al[4], bl[4];
        #pragma unroll
        for (int mi = 0; mi < 4; ++mi)
            ah[mi] = ld_frag(&AsH[(wy + mi * 16 + l15) * 40 + quad * 8]);
        #pragma unroll
        for (int ni = 0; ni < 4; ++ni)
            bh[ni] = ld_frag(&WsH[(wx + ni * 16 + l15) * 40 + quad * 8]);
        if (SPLIT) {
            #pragma unroll
            for (int mi = 0; mi < 4; ++mi)
                al[mi] = ld_frag(&AsL[(wy + mi * 16 + l15) * 40 + quad * 8]);
            #pragma unroll
            for (int ni = 0; ni < 4; ++ni)
                bl[ni] = ld_frag(&WsL[(wx + ni * 16 + l15) * 40 + quad * 8]);
        }
        #pragma unroll
        for (int mi = 0; mi < 4; ++mi)
            #pragma unroll
            for (int ni = 0; ni < 4; ++ni) {
                acc[mi][ni] = __builtin_amdgcn_mfma_f32_16x16x32_bf16(
                    ah[mi], bh[ni], acc[mi][ni], 0, 0, 0);
                if (SPLIT) {
                    acc[mi][ni] = __builtin_amdgcn_mfma_f32_16x16x32_bf16(
                        ah[mi], bl[ni], acc[mi][ni], 0, 0, 0);
                    acc[mi][ni] = __builtin_amdgcn_mfma_f32_16x16x32_bf16(
                        al[mi], bh[ni], acc[mi][ni], 0, 0, 0);
                }
            }
        __syncthreads();
    }

    // ---- epilogue ----
    #pragma unroll
    for (int mi = 0; mi < 4; ++mi) {
        #pragma unroll
        for (int r = 0; r < 4; ++r) {
            int rl = wy + mi * 16 + quad * 4 + r;
            int orow = outIdx[rl];
            if (orow < 0) continue;
            #pragma unroll
            for (int ni = 0; ni < 4; ++ni) {
                int col = n0 + wx + ni * 16 + l15;
                float val = acc[mi][ni][r] + bias[col & 1023];
                if (relu) val = fmaxf(val, 0.f);
                C[(size_t)orow * ldc + col] = val;
            }
        }
    }
}

// ---------------------------------------------------------------------------
// Split-bf16 flash attention. Block = 64 Q rows x (b,h); 4 waves x 16 Q rows.
// ---------------------------------------------------------------------------
__global__ __launch_bounds__(256) void attn_kernel(
    const float* __restrict__ Qp, int qld,
    const float* __restrict__ Kp, int kld, int kOff,
    const float* __restrict__ Vp, int vld, int vOff,
    float* __restrict__ O)
{
    __shared__ __align__(16) unsigned short KtH[64 * 72], KtL[64 * 72];
    __shared__ __align__(16) unsigned short VtH[64 * 72], VtL[64 * 72];
    __shared__ __align__(16) unsigned short PtH[4][16 * 72], PtL[4][16 * 72];

    const int tid = threadIdx.x, lane = tid & 63, wv = tid >> 6;
    const int quad = lane >> 4, l15 = lane & 15;
    const int b = blockIdx.z, h = blockIdx.y, q0 = blockIdx.x * 64;
    const int bT = b * Tn;

    // preload Q fragments hi/lo (2 k-halves of d=64)
    bf16x8 aqh[2], aql[2];
    {
        const float* qp = Qp + (size_t)(bT + q0 + wv * 16 + l15) * qld + h * 64;
        #pragma unroll
        for (int s = 0; s < 2; ++s) {
            float v[8];
            *(float4*)&v[0] = *(const float4*)(qp + s * 32 + quad * 8);
            *(float4*)&v[4] = *(const float4*)(qp + s * 32 + quad * 8 + 4);
            u16x8 th, tl;
            #pragma unroll
            for (int i = 0; i < 8; ++i) {
                unsigned short hh, ll;
                splitbf(v[i], hh, ll); th[i] = hh; tl[i] = ll;
            }
            aqh[s] = __builtin_bit_cast(bf16x8, th);
            aql[s] = __builtin_bit_cast(bf16x8, tl);
        }
    }

    f32x4 oacc[4];
    #pragma unroll
    for (int i = 0; i < 4; ++i) oacc[i] = (f32x4)0.f;
    float mrow[4] = {-1e30f, -1e30f, -1e30f, -1e30f};
    float lrow[4] = {0.f, 0.f, 0.f, 0.f};

    const int rr = tid >> 2, cc = tid & 3;

    for (int kt0 = 0; kt0 < Tn; kt0 += 64) {
        // ---- stage K [kt][d] hi/lo, V transposed [d][kt] hi/lo ----
        {
            const float* kr = Kp + (size_t)(bT + kt0 + rr) * kld + kOff + h * 64 + cc * 16;
            float v[16];
            *(float4*)&v[0]  = *(const float4*)(kr);
            *(float4*)&v[4]  = *(const float4*)(kr + 4);
            *(float4*)&v[8]  = *(const float4*)(kr + 8);
            *(float4*)&v[12] = *(const float4*)(kr + 12);
            u16x8 h0, h1, l0, l1;
            #pragma unroll
            for (int i = 0; i < 8; ++i) {
                unsigned short hh, ll;
                splitbf(v[i], hh, ll); h0[i] = hh; l0[i] = ll;
                splitbf(v[8 + i], hh, ll); h1[i] = hh; l1[i] = ll;
            }
            *(u16x8*)&KtH[rr * 72 + cc * 16]     = h0;
            *(u16x8*)&KtH[rr * 72 + cc * 16 + 8] = h1;
            *(u16x8*)&KtL[rr * 72 + cc * 16]     = l0;
            *(u16x8*)&KtL[rr * 72 + cc * 16 + 8] = l1;

            const float* vr = Vp + (size_t)(bT + kt0 + rr) * vld + vOff + h * 64 + cc * 16;
            float fv[16];
            *(float4*)&fv[0]  = *(const float4*)(vr);
            *(float4*)&fv[4]  = *(const float4*)(vr + 4);
            *(float4*)&fv[8]  = *(const float4*)(vr + 8);
            *(float4*)&fv[12] = *(const float4*)(vr + 12);
            #pragma unroll
            for (int i = 0; i < 16; ++i) {
                unsigned short hh, ll;
                splitbf(fv[i], hh, ll);
                VtH[(cc * 16 + i) * 72 + rr] = hh;
                VtL[(cc * 16 + i) * 72 + rr] = ll;
            }
        }
        __syncthreads();

        // ---- S = (Q K^T) * 0.125, split 3-term ----
        f32x4 sacc[4];
        #pragma unroll
        for (int nt = 0; nt < 4; ++nt) {
            sacc[nt] = (f32x4)0.f;
            #pragma unroll
            for (int s = 0; s < 2; ++s) {
                bf16x8 bkh = ld_frag(&KtH[(nt * 16 + l15) * 72 + s * 32 + quad * 8]);
                bf16x8 bkl = ld_frag(&KtL[(nt * 16 + l15) * 72 + s * 32 + quad * 8]);
                sacc[nt] = __builtin_amdgcn_mfma_f32_16x16x32_bf16(aqh[s], bkh, sacc[nt], 0, 0, 0);
                sacc[nt] = __builtin_amdgcn_mfma_f32_16x16x32_bf16(aqh[s], bkl, sacc[nt], 0, 0, 0);
                sacc[nt] = __builtin_amdgcn_mfma_f32_16x16x32_bf16(aql[s], bkh, sacc[nt], 0, 0, 0);
            }
        }
        #pragma unroll
        for (int nt = 0; nt < 4; ++nt)
            #pragma unroll
            for (int r = 0; r < 4; ++r) sacc[nt][r] *= 0.125f;

        // ---- online softmax ----
        float alpha[4], mnew[4];
        #pragma unroll
        for (int r = 0; r < 4; ++r) {
            float mx = fmaxf(fmaxf(sacc[0][r], sacc[1][r]), fmaxf(sacc[2][r], sacc[3][r]));
            #pragma unroll
            for (int msk = 1; msk < 16; msk <<= 1) mx = fmaxf(mx, __shfl_xor(mx, msk));
            mnew[r] = fmaxf(mrow[r], mx);
            alpha[r] = __expf(mrow[r] - mnew[r]);
            mrow[r] = mnew[r];
        }
        float rs[4] = {0.f, 0.f, 0.f, 0.f};
        #pragma unroll
        for (int nt = 0; nt < 4; ++nt)
            #pragma unroll
            for (int r = 0; r < 4; ++r) {
                float p = __expf(sacc[nt][r] - mnew[r]);
                sacc[nt][r] = p;
                rs[r] += p;
            }
        #pragma unroll
        for (int r = 0; r < 4; ++r) {
            #pragma unroll
            for (int msk = 1; msk < 16; msk <<= 1) rs[r] += __shfl_xor(rs[r], msk);
            lrow[r] = lrow[r] * alpha[r] + rs[r];
        }
        #pragma unroll
        for (int ni = 0; ni < 4; ++ni)
            #pragma unroll
            for (int r = 0; r < 4; ++r) oacc[ni][r] *= alpha[r];

        // ---- P: C-layout -> A-layout via per-wave LDS (hi/lo) ----
        #pragma unroll
        for (int nt = 0; nt < 4; ++nt)
            #pragma unroll
            for (int r = 0; r < 4; ++r) {
                unsigned short hh, ll;
                splitbf(sacc[nt][r], hh, ll);
                PtH[wv][(quad * 4 + r) * 72 + nt * 16 + l15] = hh;
                PtL[wv][(quad * 4 + r) * 72 + nt * 16 + l15] = ll;
            }
        asm volatile("s_waitcnt lgkmcnt(0)" ::: "memory");

        // ---- O += P @ V, split 3-term ----
        #pragma unroll
        for (int s = 0; s < 2; ++s) {
            bf16x8 aph = ld_frag(&PtH[wv][l15 * 72 + s * 32 + quad * 8]);
            bf16x8 apl = ld_frag(&PtL[wv][l15 * 72 + s * 32 + quad * 8]);
            #pragma unroll
            for (int ni = 0; ni < 4; ++ni) {
                bf16x8 bvh = ld_frag(&VtH[(ni * 16 + l15) * 72 + s * 32 + quad * 8]);
                bf16x8 bvl = ld_frag(&VtL[(ni * 16 + l15) * 72 + s * 32 + quad * 8]);
                oacc[ni] = __builtin_amdgcn_mfma_f32_16x16x32_bf16(aph, bvh, oacc[ni], 0, 0, 0);
                oacc[ni] = __builtin_amdgcn_mfma_f32_16x16x32_bf16(aph, bvl, oacc[ni], 0, 0, 0);
                oacc[ni] = __builtin_amdgcn_mfma_f32_16x16x32_bf16(apl, bvh, oacc[ni], 0, 0, 0);
            }
        }
        __syncthreads();
    }

    // ---- epilogue ----
    #pragma unroll
    for (int r = 0; r < 4; ++r) {
        float inv = 1.f / lrow[r];
        int orow = bT + q0 + wv * 16 + quad * 4 + r;
        #pragma unroll
        for (int ni = 0; ni < 4; ++ni) {
            int col = h * 64 + ni * 16 + l15;
            O[(size_t)orow * Dm + col] = oacc[ni][r] * inv;
        }
    }
}

// ---------------------------------------------------------------------------
// Fused residual + LayerNorm
// ---------------------------------------------------------------------------
__global__ __launch_bounds__(256) void ln_residual_kernel(
    const float* __restrict__ X, const float* __restrict__ R,
    const float* __restrict__ g, const float* __restrict__ bta,
    float* __restrict__ Out)
{
    __shared__ float red[8];
    const int t = blockIdx.x, tid = threadIdx.x;
    float v[4];
    float s = 0.f;
    #pragma unroll
    for (int i = 0; i < 4; ++i) {
        int c = tid + i * 256;
        v[i] = X[(size_t)t * Dm + c] + R[(size_t)t * Dm + c];
        s += v[i];
    }
    #pragma unroll
    for (int off = 32; off; off >>= 1) s += __shfl_down(s, off);
    const int wid = tid >> 6;
    if ((tid & 63) == 0) red[wid] = s;
    __syncthreads();
    const float mean = (red[0] + red[1] + red[2] + red[3]) * (1.f / 1024.f);
    float s2 = 0.f;
    #pragma unroll
    for (int i = 0; i < 4; ++i) { float d = v[i] - mean; s2 += d * d; }
    #pragma unroll
    for (int off = 32; off; off >>= 1) s2 += __shfl_down(s2, off);
    if ((tid & 63) == 0) red[4 + wid] = s2;
    __syncthreads();
    const float var  = (red[4] + red[5] + red[6] + red[7]) * (1.f / 1024.f);
    const float rstd = rsqrtf(var + 1e-5f);
    #pragma unroll
    for (int i = 0; i < 4; ++i) {
        int c = tid + i * 256;
        Out[(size_t)t * Dm + c] = (v[i] - mean) * rstd * g[c] + bta[c];
    }
}

// ---------------------------------------------------------------------------
// MoE router v2 — LDS-aggregated stats, block-batched atomics.
// 64 blocks x 256 threads (4 waves); each wave handles 8 tokens (dot over
// lanes=d). Per-block: LDS impf/cnt aggregation + one batch of 8 global
// atomics to reserve elist ranges, then contention-free scatter.
// ---------------------------------------------------------------------------
constexpr int RT_TPB = 32;   // tokens per block
__global__ __launch_bounds__(256) void router_kernel(
    const float* __restrict__ X, const float* __restrict__ rw,
    const float* __restrict__ rb, float* __restrict__ gatep,
    int* __restrict__ elist, int* __restrict__ ecnt,
    float* __restrict__ impf, float* __restrict__ cntf)
{
    __shared__ float simp[NE];
    __shared__ int   scnt[NE];
    __shared__ int   sbase[NE];
    __shared__ int   sexp[RT_TPB][2];
    __shared__ int   spos[RT_TPB][2];

    const int tid = threadIdx.x, lane = tid & 63, wv = tid >> 6;
    if (tid < NE) { simp[tid] = 0.f; scnt[tid] = 0; }
    __syncthreads();

    const int t0 = blockIdx.x * RT_TPB;

    for (int i = 0; i < 8; ++i) {
        const int slot = wv * 8 + i;
        const int t = t0 + slot;
        // logits: lanes over d
        float l[NE];
        #pragma unroll
        for (int e = 0; e < NE; ++e) l[e] = 0.f;
        #pragma unroll
        for (int j = 0; j < Dm / 64; ++j) {
            int d = lane + j * 64;
            float x = X[(size_t)t * Dm + d];
            #pragma unroll
            for (int e = 0; e < NE; ++e) l[e] += x * rw[d * NE + e];
        }
        #pragma unroll
        for (int e = 0; e < NE; ++e) {
            float vv = l[e];
            #pragma unroll
            for (int off = 32; off; off >>= 1) vv += __shfl_down(vv, off);
            l[e] = vv;
        }
        if (lane == 0) {
            float mx = -1e30f;
            #pragma unroll
            for (int e = 0; e < NE; ++e) { l[e] += rb[e]; mx = fmaxf(mx, l[e]); }
            float p[NE];
            float sum = 0.f;
            #pragma unroll
            for (int e = 0; e < NE; ++e) { p[e] = __expf(l[e] - mx); sum += p[e]; }
            const float inv = 1.f / sum;
            int e0 = 0, e1 = 0;
            float v0 = -1.f, v1 = -1.f;
            #pragma unroll
            for (int e = 0; e < NE; ++e) {
                float pe = p[e] * inv;
                atomicAdd(&simp[e], pe);            // LDS atomic
                if (pe > v0)      { v1 = v0; e1 = e0; v0 = pe; e0 = e; }
                else if (pe > v1) { v1 = pe; e1 = e; }
            }
            const float gs = 1.f / (v0 + v1);
            sexp[slot][0] = e0;
            sexp[slot][1] = e1;
            spos[slot][0] = atomicAdd(&scnt[e0], 1); // LDS atomic
            spos[slot][1] = atomicAdd(&scnt[e1], 1);
            gatep[2 * t]     = v0 * gs;
            gatep[2 * t + 1] = v1 * gs;
        }
    }
    __syncthreads();

    // one batch of global atomics per block
    if (tid < NE) {
        sbase[tid] = atomicAdd(&ecnt[tid], scnt[tid]);
        atomicAdd(&impf[tid], simp[tid]);
        atomicAdd(&cntf[tid], (float)scnt[tid]);
    }
    __syncthreads();

    // contention-free scatter into reserved ranges
    if (tid < RT_TPB * 2) {
        const int slot = tid >> 1, k = tid & 1;
        const int e = sexp[slot][k];
        elist[e * Nt + sbase[e] + spos[slot][k]] = 2 * (t0 + slot) + k;
    }
}

__global__ void init_kernel(int* ecnt, float* impf, float* cntf)
{
    int i = threadIdx.x;
    if (i < NE) { ecnt[i] = 0; impf[i] = 0.f; cntf[i] = 0.f; }
}

__global__ void lb_kernel(const float* __restrict__ impf,
                          const float* __restrict__ cntf,
                          float* __restrict__ out)
{
    if (threadIdx.x == 0) {
        float s = 0.f;
        for (int e = 0; e < NE; ++e) s += cntf[e] * impf[e];
        out[0] = (float)NE * s / ((float)Nt * 2.f * (float)Nt);
    }
}

__global__ __launch_bounds__(256) void moe_combine(
    const float* __restrict__ Y, const float* __restrict__ gatep,
    float* __restrict__ Out)
{
    int i = blockIdx.x * 256 + threadIdx.x;
    int t = i >> 10, c = i & 1023;
    Out[i] = gatep[2 * t] * Y[(size_t)(2 * t) * Dm + c]
           + gatep[2 * t + 1] * Y[(size_t)(2 * t + 1) * Dm + c];
}

// ---------------------------------------------------------------------------
extern "C" void kernel_launch(void* const* d_in, const int* in_sizes, int n_in,
                              void* d_out, int out_size, void* d_ws, size_t ws_size,
                              hipStream_t stream)
{
    const float* tgt   = (const float*)d_in[0];
    const float* memry = (const float*)d_in[1];
    const float* sa_wq = (const float*)d_in[2];
    const float* sa_wk = (const float*)d_in[3];
    const float* sa_wv = (const float*)d_in[4];
    const float* sa_wo = (const float*)d_in[5];
    const float* ca_wq = (const float*)d_in[6];
    const float* ca_wk = (const float*)d_in[7];
    const float* ca_wv = (const float*)d_in[8];
    const float* ca_wo = (const float*)d_in[9];
    const float* sa_bq = (const float*)d_in[10];
    const float* sa_bk = (const float*)d_in[11];
    const float* sa_bv = (const float*)d_in[12];
    const float* sa_bo = (const float*)d_in[13];
    const float* ca_bq = (const float*)d_in[14];
    const float* ca_bk = (const float*)d_in[15];
    const float* ca_bv = (const float*)d_in[16];
    const float* ca_bo = (const float*)d_in[17];
    const float* ln1_g = (const float*)d_in[18];
    const float* ln2_g = (const float*)d_in[19];
    const float* ln3_g = (const float*)d_in[20];
    const float* ln1_b = (const float*)d_in[21];
    const float* ln2_b = (const float*)d_in[22];
    const float* ln3_b = (const float*)d_in[23];
    const float* rw    = (const float*)d_in[24];
    const float* rb    = (const float*)d_in[25];
    const float* w1    = (const float*)d_in[26];
    const float* b1    = (const float*)d_in[27];
    const float* w2    = (const float*)d_in[28];
    const float* b2    = (const float*)d_in[29];

    float* ws = (float*)d_ws;
    const size_t ND = (size_t)Nt * Dm;
    float* qkv  = ws;                         // 3*ND
    float* qc   = ws;
    float* kvc  = ws + ND;
    float* attnO = ws + 3 * ND;               // ND
    float* hbuf = ws;                         // 4*ND (aliases, dead by MoE)
    float* t2   = ws + 4 * ND;                // ND
    float* tb   = ws + 5 * ND;                // ND
    float* ybuf = ws + 6 * ND;                // 2*ND
    float* gatep = ws + 8 * ND;               // 2*Nt
    int*   elist = (int*)(gatep + 2 * Nt);    // NE*Nt
    int*   ecnt  = elist + NE * Nt;           // NE
    float* impf  = (float*)(ecnt + NE);       // NE
    float* cntf  = impf + NE;                 // NE
    float* outp  = (float*)d_out;

    dim3 blk(256);
    dim3 attnGrid(Tn / 64, NH, Bn);

    // ---- self-attention ----
    gemm_bf16_kernel<1><<<dim3(24, 16, 1), blk, 0, stream>>>(
        tgt, Dm, sa_wq, sa_wk, sa_wv, Dm, 0, sa_bq, sa_bk, sa_bv, 0,
        qkv, 3 * Dm, Nt, Dm, nullptr, 0, nullptr, 0, 0);
    attn_kernel<<<attnGrid, blk, 0, stream>>>(
        qkv, 3 * Dm, qkv, 3 * Dm, 1024, qkv, 3 * Dm, 2048, attnO);
    gemm_bf16_kernel<1><<<dim3(8, 16, 1), blk, 0, stream>>>(
        attnO, Dm, sa_wo, sa_wo, sa_wo, Dm, 0, sa_bo, sa_bo, sa_bo, 0,
        t2, Dm, Nt, Dm, nullptr, 0, nullptr, 0, 0);
    ln_residual_kernel<<<Nt, blk, 0, stream>>>(tgt, t2, ln1_g, ln1_b, tb);

    // ---- cross-attention ----
    gemm_bf16_kernel<1><<<dim3(8, 16, 1), blk, 0, stream>>>(
        tb, Dm, ca_wq, ca_wq, ca_wq, Dm, 0, ca_bq, ca_bq, ca_bq, 0,
        qc, Dm, Nt, Dm, nullptr, 0, nullptr, 0, 0);
    gemm_bf16_kernel<1><<<dim3(16, 16, 1), blk, 0, stream>>>(
        memry, Dm, ca_wk, ca_wv, ca_wv, Dm, 0, ca_bk, ca_bv, ca_bv, 0,
        kvc, 2 * Dm, Nt, Dm, nullptr, 0, nullptr, 0, 0);
    attn_kernel<<<attnGrid, blk, 0, stream>>>(
        qc, Dm, kvc, 2 * Dm, 0, kvc, 2 * Dm, 1024, attnO);
    gemm_bf16_kernel<1><<<dim3(8, 16, 1), blk, 0, stream>>>(
        attnO, Dm, ca_wo, ca_wo, ca_wo, Dm, 0, ca_bo, ca_bo, ca_bo, 0,
        t2, Dm, Nt, Dm, nullptr, 0, nullptr, 0, 0);
    ln_residual_kernel<<<Nt, blk, 0, stream>>>(tb, t2, ln2_g, ln2_b, tb);

    // ---- MoE ----
    init_kernel<<<1, 64, 0, stream>>>(ecnt, impf, cntf);
    router_kernel<<<Nt / RT_TPB, blk, 0, stream>>>(tb, rw, rb, gatep, elist, ecnt, impf, cntf);
    gemm_bf16_kernel<1><<<dim3(16, 16, 8), blk, 0, stream>>>(
        tb, Dm, w1, w1 + 1024, w1 + 1024, Ff, (size_t)Dm * Ff, b1, b1 + 1024, b1 + 1024, Ff,
        hbuf, Ff, 0, Dm, elist, Nt, ecnt, 1, 1);
    gemm_bf16_kernel<1><<<dim3(8, 16, 8), blk, 0, stream>>>(
        hbuf, Ff, w2, w2, w2, Dm, (size_t)Ff * Dm, b2, b2, b2, Dm,
        ybuf, Dm, 0, Ff, elist, Nt, ecnt, 2, 0);
    moe_combine<<<(Nt * Dm) / 256, blk, 0, stream>>>(ybuf, gatep, t2);
    ln_residual_kernel<<<Nt, blk, 0, stream>>>(tb, t2, ln3_g, ln3_b, outp);
    lb_kernel<<<1, 64, 0, stream>>>(impf, cntf, outp + ND);
}

// Round 5
// 830.695 us; speedup vs baseline: 4.3661x; 1.0786x over previous
//
#include <hip/hip_runtime.h>

// Problem constants
constexpr int Dm = 1024;
constexpr int NH = 16;
constexpr int Ff = 2048;
constexpr int NE = 8;
constexpr int Bn = 4;
constexpr int Tn = 512;
constexpr int Nt = 2048;   // total tokens

typedef float  f32x4  __attribute__((ext_vector_type(4)));
typedef __bf16 bf16x8 __attribute__((ext_vector_type(8)));
typedef unsigned short u16x8 __attribute__((ext_vector_type(8)));

// fp32 -> bf16 round-to-nearest-even
__device__ inline unsigned short f2bf(float f) {
    unsigned u = __builtin_bit_cast(unsigned, f);
    u += 0x7FFFu + ((u >> 16) & 1u);
    return (unsigned short)(u >> 16);
}
__device__ inline float bf2f(unsigned short h) {
    unsigned u = (unsigned)h << 16;
    return __builtin_bit_cast(float, u);
}
// split x = hi + lo (hi,lo bf16; residual ~2^-18 relative)
__device__ inline void splitbf(float x, unsigned short& hi, unsigned short& lo) {
    hi = f2bf(x);
    lo = f2bf(x - bf2f(hi));
}
__device__ inline bf16x8 ld_frag(const unsigned short* p) {
    return __builtin_bit_cast(bf16x8, *(const u16x8*)p);
}

// ---------------------------------------------------------------------------
// MFMA GEMM: C = act(A @ W + bias). Tile 128x128x32, 4 waves.
//  SPLIT: 1 = fp32-grade via 3-term split-bf16 (AhBh+AhBl+AlBh), 0 = single.
//  ABF:   1 = A is pre-converted bf16 (u16), 0 = A is fp32 (convert inline).
//  CBF:   1 = C written as bf16 (u16), 0 = fp32.
// W as up-to-3 1024-col fp32 segments. Gather modes: 0 dense, 1 ffn1, 2 ffn2.
// ---------------------------------------------------------------------------
template <int SPLIT, int ABF, int CBF>
__global__ __launch_bounds__(256) void gemm_bf16_kernel(
    const void* __restrict__ Ain, int lda,
    const float* __restrict__ W0, const float* __restrict__ W1,
    const float* __restrict__ W2, int ldw, size_t weStride,
    const float* __restrict__ B0, const float* __restrict__ B1,
    const float* __restrict__ B2, size_t beStride,
    void* __restrict__ Cout, int ldc,
    int Mparam, int K,
    const int* __restrict__ lst, int lstStride, const int* __restrict__ cnt,
    int mode, int relu)
{
    __shared__ __align__(16) unsigned short AsH[128 * 40];
    __shared__ __align__(16) unsigned short WsH[128 * 40];
    __shared__ __align__(16) unsigned short AsL[SPLIT ? 128 * 40 : 1];
    __shared__ __align__(16) unsigned short WsL[SPLIT ? 128 * 40 : 1];
    __shared__ int inIdx[128];
    __shared__ int outIdx[128];

    const int e = blockIdx.z;
    const int M = (mode == 0) ? Mparam : cnt[e];
    const int m0 = blockIdx.y * 128;
    if (m0 >= M) return;
    const int n0 = blockIdx.x * 128;
    const int seg = n0 >> 10;
    const float* W = ((seg == 0) ? W0 : (seg == 1) ? W1 : W2) + (size_t)e * weStride;
    const float* bias = ((seg == 0) ? B0 : (seg == 1) ? B1 : B2) + (size_t)e * beStride;
    const int nseg = n0 & 1023;
    const int tid = threadIdx.x;

    if (tid < 128) {
        int g = m0 + tid;
        bool valid = g < M;
        int gi, go;
        if (mode == 0) { gi = valid ? g : (M - 1); go = valid ? g : -1; }
        else {
            int pid = lst[(size_t)e * lstStride + (valid ? g : 0)];
            gi = (mode == 1) ? (pid >> 1) : pid;
            go = valid ? pid : -1;
        }
        inIdx[tid] = gi;
        outIdx[tid] = go;
    }
    __syncthreads();

    const int ar = tid >> 1, ahalf = tid & 1;                  // A: 2 thr/row
    const int bn = (tid & 63) * 2, bko = ((tid >> 6) & 3) * 8; // B: 2 n, 8 k
    const float* aBaseF = ABF ? nullptr
        : ((const float*)Ain + (size_t)inIdx[ar] * lda + ahalf * 16);
    const unsigned short* aBaseB = ABF
        ? ((const unsigned short*)Ain + (size_t)inIdx[ar] * lda + ahalf * 16)
        : nullptr;
    const float* wBase = W + (size_t)bko * ldw + nseg + bn;

    const int lane = tid & 63, wv = tid >> 6;
    const int wy = (wv >> 1) * 64, wx = (wv & 1) * 64;
    const int l15 = lane & 15, quad = lane >> 4;

    f32x4 acc[4][4];
    #pragma unroll
    for (int i = 0; i < 4; ++i)
        #pragma unroll
        for (int j = 0; j < 4; ++j) acc[i][j] = (f32x4)0.f;

    for (int k0 = 0; k0 < K; k0 += 32) {
        // ---- stage A tile [m][k] ----
        if (ABF) {
            const unsigned short* ap = aBaseB + k0;
            *(u16x8*)&AsH[ar * 40 + ahalf * 16]     = *(const u16x8*)(ap);
            *(u16x8*)&AsH[ar * 40 + ahalf * 16 + 8] = *(const u16x8*)(ap + 8);
        } else {
            const float* ap = aBaseF + k0;
            float v[16];
            *(float4*)&v[0]  = *(const float4*)(ap);
            *(float4*)&v[4]  = *(const float4*)(ap + 4);
            *(float4*)&v[8]  = *(const float4*)(ap + 8);
            *(float4*)&v[12] = *(const float4*)(ap + 12);
            u16x8 h0, h1, l0, l1;
            #pragma unroll
            for (int i = 0; i < 8; ++i) {
                unsigned short hh, ll;
                splitbf(v[i], hh, ll); h0[i] = hh; l0[i] = ll;
                splitbf(v[8 + i], hh, ll); h1[i] = hh; l1[i] = ll;
            }
            *(u16x8*)&AsH[ar * 40 + ahalf * 16]     = h0;
            *(u16x8*)&AsH[ar * 40 + ahalf * 16 + 8] = h1;
            if (SPLIT) {
                *(u16x8*)&AsL[ar * 40 + ahalf * 16]     = l0;
                *(u16x8*)&AsL[ar * 40 + ahalf * 16 + 8] = l1;
            }
        }
        // ---- stage W tile transposed [n][k] ----
        {
            const float* wp = wBase + (size_t)k0 * ldw;
            float2 wr[8];
            #pragma unroll
            for (int j = 0; j < 8; ++j) wr[j] = *(const float2*)(wp + (size_t)j * ldw);
            u16x8 h0, h1, l0, l1;
            #pragma unroll
            for (int j = 0; j < 8; ++j) {
                if (SPLIT) {
                    unsigned short hh, ll;
                    splitbf(wr[j].x, hh, ll); h0[j] = hh; l0[j] = ll;
                    splitbf(wr[j].y, hh, ll); h1[j] = hh; l1[j] = ll;
                } else {
                    h0[j] = f2bf(wr[j].x);
                    h1[j] = f2bf(wr[j].y);
                }
            }
            *(u16x8*)&WsH[bn * 40 + bko]       = h0;
            *(u16x8*)&WsH[(bn + 1) * 40 + bko] = h1;
            if (SPLIT) {
                *(u16x8*)&WsL[bn * 40 + bko]       = l0;
                *(u16x8*)&WsL[(bn + 1) * 40 + bko] = l1;
            }
        }
        __syncthreads();
        // ---- fragments + MFMA ----
        bf16x8 ah[4], bh[4], al[4], bl[4];
        #pragma unroll
        for (int mi = 0; mi < 4; ++mi)
            ah[mi] = ld_frag(&AsH[(wy + mi * 16 + l15) * 40 + quad * 8]);
        #pragma unroll
        for (int ni = 0; ni < 4; ++ni)
            bh[ni] = ld_frag(&WsH[(wx + ni * 16 + l15) * 40 + quad * 8]);
        if (SPLIT) {
            #pragma unroll
            for (int mi = 0; mi < 4; ++mi)
                al[mi] = ld_frag(&AsL[(wy + mi * 16 + l15) * 40 + quad * 8]);
            #pragma unroll
            for (int ni = 0; ni < 4; ++ni)
                bl[ni] = ld_frag(&WsL[(wx + ni * 16 + l15) * 40 + quad * 8]);
        }
        #pragma unroll
        for (int mi = 0; mi < 4; ++mi)
            #pragma unroll
            for (int ni = 0; ni < 4; ++ni) {
                acc[mi][ni] = __builtin_amdgcn_mfma_f32_16x16x32_bf16(
                    ah[mi], bh[ni], acc[mi][ni], 0, 0, 0);
                if (SPLIT) {
                    acc[mi][ni] = __builtin_amdgcn_mfma_f32_16x16x32_bf16(
                        ah[mi], bl[ni], acc[mi][ni], 0, 0, 0);
                    acc[mi][ni] = __builtin_amdgcn_mfma_f32_16x16x32_bf16(
                        al[mi], bh[ni], acc[mi][ni], 0, 0, 0);
                }
            }
        __syncthreads();
    }

    // ---- epilogue ----
    #pragma unroll
    for (int mi = 0; mi < 4; ++mi) {
        #pragma unroll
        for (int r = 0; r < 4; ++r) {
            int rl = wy + mi * 16 + quad * 4 + r;
            int orow = outIdx[rl];
            if (orow < 0) continue;
            #pragma unroll
            for (int ni = 0; ni < 4; ++ni) {
                int col = n0 + wx + ni * 16 + l15;
                float val = acc[mi][ni][r] + bias[col & 1023];
                if (relu) val = fmaxf(val, 0.f);
                if (CBF)
                    ((unsigned short*)Cout)[(size_t)orow * ldc + col] = f2bf(val);
                else
                    ((float*)Cout)[(size_t)orow * ldc + col] = val;
            }
        }
    }
}

// ---------------------------------------------------------------------------
// Split-bf16 flash attention. Block = 64 Q rows x (b,h); 4 waves x 16 Q rows.
// ---------------------------------------------------------------------------
__global__ __launch_bounds__(256) void attn_kernel(
    const float* __restrict__ Qp, int qld,
    const float* __restrict__ Kp, int kld, int kOff,
    const float* __restrict__ Vp, int vld, int vOff,
    float* __restrict__ O)
{
    __shared__ __align__(16) unsigned short KtH[64 * 72], KtL[64 * 72];
    __shared__ __align__(16) unsigned short VtH[64 * 72], VtL[64 * 72];
    __shared__ __align__(16) unsigned short PtH[4][16 * 72], PtL[4][16 * 72];

    const int tid = threadIdx.x, lane = tid & 63, wv = tid >> 6;
    const int quad = lane >> 4, l15 = lane & 15;
    const int b = blockIdx.z, h = blockIdx.y, q0 = blockIdx.x * 64;
    const int bT = b * Tn;

    // preload Q fragments hi/lo (2 k-halves of d=64)
    bf16x8 aqh[2], aql[2];
    {
        const float* qp = Qp + (size_t)(bT + q0 + wv * 16 + l15) * qld + h * 64;
        #pragma unroll
        for (int s = 0; s < 2; ++s) {
            float v[8];
            *(float4*)&v[0] = *(const float4*)(qp + s * 32 + quad * 8);
            *(float4*)&v[4] = *(const float4*)(qp + s * 32 + quad * 8 + 4);
            u16x8 th, tl;
            #pragma unroll
            for (int i = 0; i < 8; ++i) {
                unsigned short hh, ll;
                splitbf(v[i], hh, ll); th[i] = hh; tl[i] = ll;
            }
            aqh[s] = __builtin_bit_cast(bf16x8, th);
            aql[s] = __builtin_bit_cast(bf16x8, tl);
        }
    }

    f32x4 oacc[4];
    #pragma unroll
    for (int i = 0; i < 4; ++i) oacc[i] = (f32x4)0.f;
    float mrow[4] = {-1e30f, -1e30f, -1e30f, -1e30f};
    float lrow[4] = {0.f, 0.f, 0.f, 0.f};

    const int rr = tid >> 2, cc = tid & 3;

    for (int kt0 = 0; kt0 < Tn; kt0 += 64) {
        // ---- stage K [kt][d] hi/lo, V transposed [d][kt] hi/lo ----
        {
            const float* kr = Kp + (size_t)(bT + kt0 + rr) * kld + kOff + h * 64 + cc * 16;
            float v[16];
            *(float4*)&v[0]  = *(const float4*)(kr);
            *(float4*)&v[4]  = *(const float4*)(kr + 4);
            *(float4*)&v[8]  = *(const float4*)(kr + 8);
            *(float4*)&v[12] = *(const float4*)(kr + 12);
            u16x8 h0, h1, l0, l1;
            #pragma unroll
            for (int i = 0; i < 8; ++i) {
                unsigned short hh, ll;
                splitbf(v[i], hh, ll); h0[i] = hh; l0[i] = ll;
                splitbf(v[8 + i], hh, ll); h1[i] = hh; l1[i] = ll;
            }
            *(u16x8*)&KtH[rr * 72 + cc * 16]     = h0;
            *(u16x8*)&KtH[rr * 72 + cc * 16 + 8] = h1;
            *(u16x8*)&KtL[rr * 72 + cc * 16]     = l0;
            *(u16x8*)&KtL[rr * 72 + cc * 16 + 8] = l1;

            const float* vr = Vp + (size_t)(bT + kt0 + rr) * vld + vOff + h * 64 + cc * 16;
            float fv[16];
            *(float4*)&fv[0]  = *(const float4*)(vr);
            *(float4*)&fv[4]  = *(const float4*)(vr + 4);
            *(float4*)&fv[8]  = *(const float4*)(vr + 8);
            *(float4*)&fv[12] = *(const float4*)(vr + 12);
            #pragma unroll
            for (int i = 0; i < 16; ++i) {
                unsigned short hh, ll;
                splitbf(fv[i], hh, ll);
                VtH[(cc * 16 + i) * 72 + rr] = hh;
                VtL[(cc * 16 + i) * 72 + rr] = ll;
            }
        }
        __syncthreads();

        // ---- S = (Q K^T) * 0.125, split 3-term ----
        f32x4 sacc[4];
        #pragma unroll
        for (int nt = 0; nt < 4; ++nt) {
            sacc[nt] = (f32x4)0.f;
            #pragma unroll
            for (int s = 0; s < 2; ++s) {
                bf16x8 bkh = ld_frag(&KtH[(nt * 16 + l15) * 72 + s * 32 + quad * 8]);
                bf16x8 bkl = ld_frag(&KtL[(nt * 16 + l15) * 72 + s * 32 + quad * 8]);
                sacc[nt] = __builtin_amdgcn_mfma_f32_16x16x32_bf16(aqh[s], bkh, sacc[nt], 0, 0, 0);
                sacc[nt] = __builtin_amdgcn_mfma_f32_16x16x32_bf16(aqh[s], bkl, sacc[nt], 0, 0, 0);
                sacc[nt] = __builtin_amdgcn_mfma_f32_16x16x32_bf16(aql[s], bkh, sacc[nt], 0, 0, 0);
            }
        }
        #pragma unroll
        for (int nt = 0; nt < 4; ++nt)
            #pragma unroll
            for (int r = 0; r < 4; ++r) sacc[nt][r] *= 0.125f;

        // ---- online softmax ----
        float alpha[4], mnew[4];
        #pragma unroll
        for (int r = 0; r < 4; ++r) {
            float mx = fmaxf(fmaxf(sacc[0][r], sacc[1][r]), fmaxf(sacc[2][r], sacc[3][r]));
            #pragma unroll
            for (int msk = 1; msk < 16; msk <<= 1) mx = fmaxf(mx, __shfl_xor(mx, msk));
            mnew[r] = fmaxf(mrow[r], mx);
            alpha[r] = __expf(mrow[r] - mnew[r]);
            mrow[r] = mnew[r];
        }
        float rs[4] = {0.f, 0.f, 0.f, 0.f};
        #pragma unroll
        for (int nt = 0; nt < 4; ++nt)
            #pragma unroll
            for (int r = 0; r < 4; ++r) {
                float p = __expf(sacc[nt][r] - mnew[r]);
                sacc[nt][r] = p;
                rs[r] += p;
            }
        #pragma unroll
        for (int r = 0; r < 4; ++r) {
            #pragma unroll
            for (int msk = 1; msk < 16; msk <<= 1) rs[r] += __shfl_xor(rs[r], msk);
            lrow[r] = lrow[r] * alpha[r] + rs[r];
        }
        #pragma unroll
        for (int ni = 0; ni < 4; ++ni)
            #pragma unroll
            for (int r = 0; r < 4; ++r) oacc[ni][r] *= alpha[r];

        // ---- P: C-layout -> A-layout via per-wave LDS (hi/lo) ----
        #pragma unroll
        for (int nt = 0; nt < 4; ++nt)
            #pragma unroll
            for (int r = 0; r < 4; ++r) {
                unsigned short hh, ll;
                splitbf(sacc[nt][r], hh, ll);
                PtH[wv][(quad * 4 + r) * 72 + nt * 16 + l15] = hh;
                PtL[wv][(quad * 4 + r) * 72 + nt * 16 + l15] = ll;
            }
        asm volatile("s_waitcnt lgkmcnt(0)" ::: "memory");

        // ---- O += P @ V, split 3-term ----
        #pragma unroll
        for (int s = 0; s < 2; ++s) {
            bf16x8 aph = ld_frag(&PtH[wv][l15 * 72 + s * 32 + quad * 8]);
            bf16x8 apl = ld_frag(&PtL[wv][l15 * 72 + s * 32 + quad * 8]);
            #pragma unroll
            for (int ni = 0; ni < 4; ++ni) {
                bf16x8 bvh = ld_frag(&VtH[(ni * 16 + l15) * 72 + s * 32 + quad * 8]);
                bf16x8 bvl = ld_frag(&VtL[(ni * 16 + l15) * 72 + s * 32 + quad * 8]);
                oacc[ni] = __builtin_amdgcn_mfma_f32_16x16x32_bf16(aph, bvh, oacc[ni], 0, 0, 0);
                oacc[ni] = __builtin_amdgcn_mfma_f32_16x16x32_bf16(aph, bvl, oacc[ni], 0, 0, 0);
                oacc[ni] = __builtin_amdgcn_mfma_f32_16x16x32_bf16(apl, bvh, oacc[ni], 0, 0, 0);
            }
        }
        __syncthreads();
    }

    // ---- epilogue ----
    #pragma unroll
    for (int r = 0; r < 4; ++r) {
        float inv = 1.f / lrow[r];
        int orow = bT + q0 + wv * 16 + quad * 4 + r;
        #pragma unroll
        for (int ni = 0; ni < 4; ++ni) {
            int col = h * 64 + ni * 16 + l15;
            O[(size_t)orow * Dm + col] = oacc[ni][r] * inv;
        }
    }
}

// ---------------------------------------------------------------------------
// Fused residual + LayerNorm
// ---------------------------------------------------------------------------
__global__ __launch_bounds__(256) void ln_residual_kernel(
    const float* __restrict__ X, const float* __restrict__ R,
    const float* __restrict__ g, const float* __restrict__ bta,
    float* __restrict__ Out)
{
    __shared__ float red[8];
    const int t = blockIdx.x, tid = threadIdx.x;
    float v[4];
    float s = 0.f;
    #pragma unroll
    for (int i = 0; i < 4; ++i) {
        int c = tid + i * 256;
        v[i] = X[(size_t)t * Dm + c] + R[(size_t)t * Dm + c];
        s += v[i];
    }
    #pragma unroll
    for (int off = 32; off; off >>= 1) s += __shfl_down(s, off);
    const int wid = tid >> 6;
    if ((tid & 63) == 0) red[wid] = s;
    __syncthreads();
    const float mean = (red[0] + red[1] + red[2] + red[3]) * (1.f / 1024.f);
    float s2 = 0.f;
    #pragma unroll
    for (int i = 0; i < 4; ++i) { float d = v[i] - mean; s2 += d * d; }
    #pragma unroll
    for (int off = 32; off; off >>= 1) s2 += __shfl_down(s2, off);
    if ((tid & 63) == 0) red[4 + wid] = s2;
    __syncthreads();
    const float var  = (red[4] + red[5] + red[6] + red[7]) * (1.f / 1024.f);
    const float rstd = rsqrtf(var + 1e-5f);
    #pragma unroll
    for (int i = 0; i < 4; ++i) {
        int c = tid + i * 256;
        Out[(size_t)t * Dm + c] = (v[i] - mean) * rstd * g[c] + bta[c];
    }
}

// ---------------------------------------------------------------------------
// MoE router — LDS-aggregated stats, block-batched atomics.
// ---------------------------------------------------------------------------
constexpr int RT_TPB = 32;   // tokens per block
__global__ __launch_bounds__(256) void router_kernel(
    const float* __restrict__ X, const float* __restrict__ rw,
    const float* __restrict__ rb, float* __restrict__ gatep,
    int* __restrict__ elist, int* __restrict__ ecnt,
    float* __restrict__ impf, float* __restrict__ cntf)
{
    __shared__ float simp[NE];
    __shared__ int   scnt[NE];
    __shared__ int   sbase[NE];
    __shared__ int   sexp[RT_TPB][2];
    __shared__ int   spos[RT_TPB][2];

    const int tid = threadIdx.x, lane = tid & 63, wv = tid >> 6;
    if (tid < NE) { simp[tid] = 0.f; scnt[tid] = 0; }
    __syncthreads();

    const int t0 = blockIdx.x * RT_TPB;

    for (int i = 0; i < 8; ++i) {
        const int slot = wv * 8 + i;
        const int t = t0 + slot;
        float l[NE];
        #pragma unroll
        for (int e = 0; e < NE; ++e) l[e] = 0.f;
        #pragma unroll
        for (int j = 0; j < Dm / 64; ++j) {
            int d = lane + j * 64;
            float x = X[(size_t)t * Dm + d];
            #pragma unroll
            for (int e = 0; e < NE; ++e) l[e] += x * rw[d * NE + e];
        }
        #pragma unroll
        for (int e = 0; e < NE; ++e) {
            float vv = l[e];
            #pragma unroll
            for (int off = 32; off; off >>= 1) vv += __shfl_down(vv, off);
            l[e] = vv;
        }
        if (lane == 0) {
            float mx = -1e30f;
            #pragma unroll
            for (int e = 0; e < NE; ++e) { l[e] += rb[e]; mx = fmaxf(mx, l[e]); }
            float p[NE];
            float sum = 0.f;
            #pragma unroll
            for (int e = 0; e < NE; ++e) { p[e] = __expf(l[e] - mx); sum += p[e]; }
            const float inv = 1.f / sum;
            int e0 = 0, e1 = 0;
            float v0 = -1.f, v1 = -1.f;
            #pragma unroll
            for (int e = 0; e < NE; ++e) {
                float pe = p[e] * inv;
                atomicAdd(&simp[e], pe);
                if (pe > v0)      { v1 = v0; e1 = e0; v0 = pe; e0 = e; }
                else if (pe > v1) { v1 = pe; e1 = e; }
            }
            const float gs = 1.f / (v0 + v1);
            sexp[slot][0] = e0;
            sexp[slot][1] = e1;
            spos[slot][0] = atomicAdd(&scnt[e0], 1);
            spos[slot][1] = atomicAdd(&scnt[e1], 1);
            gatep[2 * t]     = v0 * gs;
            gatep[2 * t + 1] = v1 * gs;
        }
    }
    __syncthreads();

    if (tid < NE) {
        sbase[tid] = atomicAdd(&ecnt[tid], scnt[tid]);
        atomicAdd(&impf[tid], simp[tid]);
        atomicAdd(&cntf[tid], (float)scnt[tid]);
    }
    __syncthreads();

    if (tid < RT_TPB * 2) {
        const int slot = tid >> 1, k = tid & 1;
        const int e = sexp[slot][k];
        elist[e * Nt + sbase[e] + spos[slot][k]] = 2 * (t0 + slot) + k;
    }
}

__global__ void init_kernel(int* ecnt, float* impf, float* cntf)
{
    int i = threadIdx.x;
    if (i < NE) { ecnt[i] = 0; impf[i] = 0.f; cntf[i] = 0.f; }
}

__global__ void lb_kernel(const float* __restrict__ impf,
                          const float* __restrict__ cntf,
                          float* __restrict__ out)
{
    if (threadIdx.x == 0) {
        float s = 0.f;
        for (int e = 0; e < NE; ++e) s += cntf[e] * impf[e];
        out[0] = (float)NE * s / ((float)Nt * 2.f * (float)Nt);
    }
}

__global__ __launch_bounds__(256) void moe_combine(
    const float* __restrict__ Y, const float* __restrict__ gatep,
    float* __restrict__ Out)
{
    int i = blockIdx.x * 256 + threadIdx.x;
    int t = i >> 10, c = i & 1023;
    Out[i] = gatep[2 * t] * Y[(size_t)(2 * t) * Dm + c]
           + gatep[2 * t + 1] * Y[(size_t)(2 * t + 1) * Dm + c];
}

// ---------------------------------------------------------------------------
extern "C" void kernel_launch(void* const* d_in, const int* in_sizes, int n_in,
                              void* d_out, int out_size, void* d_ws, size_t ws_size,
                              hipStream_t stream)
{
    const float* tgt   = (const float*)d_in[0];
    const float* memry = (const float*)d_in[1];
    const float* sa_wq = (const float*)d_in[2];
    const float* sa_wk = (const float*)d_in[3];
    const float* sa_wv = (const float*)d_in[4];
    const float* sa_wo = (const float*)d_in[5];
    const float* ca_wq = (const float*)d_in[6];
    const float* ca_wk = (const float*)d_in[7];
    const float* ca_wv = (const float*)d_in[8];
    const float* ca_wo = (const float*)d_in[9];
    const float* sa_bq = (const float*)d_in[10];
    const float* sa_bk = (const float*)d_in[11];
    const float* sa_bv = (const float*)d_in[12];
    const float* sa_bo = (const float*)d_in[13];
    const float* ca_bq = (const float*)d_in[14];
    const float* ca_bk = (const float*)d_in[15];
    const float* ca_bv = (const float*)d_in[16];
    const float* ca_bo = (const float*)d_in[17];
    const float* ln1_g = (const float*)d_in[18];
    const float* ln2_g = (const float*)d_in[19];
    const float* ln3_g = (const float*)d_in[20];
    const float* ln1_b = (const float*)d_in[21];
    const float* ln2_b = (const float*)d_in[22];
    const float* ln3_b = (const float*)d_in[23];
    const float* rw    = (const float*)d_in[24];
    const float* rb    = (const float*)d_in[25];
    const float* w1    = (const float*)d_in[26];
    const float* b1    = (const float*)d_in[27];
    const float* w2    = (const float*)d_in[28];
    const float* b2    = (const float*)d_in[29];

    float* ws = (float*)d_ws;
    const size_t ND = (size_t)Nt * Dm;
    float* qkv  = ws;                         // 3*ND
    float* qc   = ws;
    float* kvc  = ws + ND;
    float* attnO = ws + 3 * ND;               // ND
    unsigned short* hbuf16 = (unsigned short*)ws;  // 4096 x Ff bf16 = 16 MB (aliases qkv; dead by MoE)
    float* t2   = ws + 4 * ND;                // ND
    float* tb   = ws + 5 * ND;                // ND
    float* ybuf = ws + 6 * ND;                // 2*ND
    float* gatep = ws + 8 * ND;               // 2*Nt
    int*   elist = (int*)(gatep + 2 * Nt);    // NE*Nt
    int*   ecnt  = elist + NE * Nt;           // NE
    float* impf  = (float*)(ecnt + NE);       // NE
    float* cntf  = impf + NE;                 // NE
    float* outp  = (float*)d_out;

    dim3 blk(256);
    dim3 attnGrid(Tn / 64, NH, Bn);

    // ---- self-attention ----
    gemm_bf16_kernel<1, 0, 0><<<dim3(24, 16, 1), blk, 0, stream>>>(
        tgt, Dm, sa_wq, sa_wk, sa_wv, Dm, 0, sa_bq, sa_bk, sa_bv, 0,
        qkv, 3 * Dm, Nt, Dm, nullptr, 0, nullptr, 0, 0);
    attn_kernel<<<attnGrid, blk, 0, stream>>>(
        qkv, 3 * Dm, qkv, 3 * Dm, 1024, qkv, 3 * Dm, 2048, attnO);
    gemm_bf16_kernel<1, 0, 0><<<dim3(8, 16, 1), blk, 0, stream>>>(
        attnO, Dm, sa_wo, sa_wo, sa_wo, Dm, 0, sa_bo, sa_bo, sa_bo, 0,
        t2, Dm, Nt, Dm, nullptr, 0, nullptr, 0, 0);
    ln_residual_kernel<<<Nt, blk, 0, stream>>>(tgt, t2, ln1_g, ln1_b, tb);

    // ---- cross-attention ----
    gemm_bf16_kernel<1, 0, 0><<<dim3(8, 16, 1), blk, 0, stream>>>(
        tb, Dm, ca_wq, ca_wq, ca_wq, Dm, 0, ca_bq, ca_bq, ca_bq, 0,
        qc, Dm, Nt, Dm, nullptr, 0, nullptr, 0, 0);
    gemm_bf16_kernel<1, 0, 0><<<dim3(16, 16, 1), blk, 0, stream>>>(
        memry, Dm, ca_wk, ca_wv, ca_wv, Dm, 0, ca_bk, ca_bv, ca_bv, 0,
        kvc, 2 * Dm, Nt, Dm, nullptr, 0, nullptr, 0, 0);
    attn_kernel<<<attnGrid, blk, 0, stream>>>(
        qc, Dm, kvc, 2 * Dm, 0, kvc, 2 * Dm, 1024, attnO);
    gemm_bf16_kernel<1, 0, 0><<<dim3(8, 16, 1), blk, 0, stream>>>(
        attnO, Dm, ca_wo, ca_wo, ca_wo, Dm, 0, ca_bo, ca_bo, ca_bo, 0,
        t2, Dm, Nt, Dm, nullptr, 0, nullptr, 0, 0);
    ln_residual_kernel<<<Nt, blk, 0, stream>>>(tb, t2, ln2_g, ln2_b, tb);

    // ---- MoE (FFNs single-bf16: downstream of router, smooth error only) ----
    init_kernel<<<1, 64, 0, stream>>>(ecnt, impf, cntf);
    router_kernel<<<Nt / RT_TPB, blk, 0, stream>>>(tb, rw, rb, gatep, elist, ecnt, impf, cntf);
    // ffn1: H[pid] = relu(tb[pid>>1] @ w1[e] + b1[e]) -> bf16 H
    gemm_bf16_kernel<0, 0, 1><<<dim3(16, 16, 8), blk, 0, stream>>>(
        tb, Dm, w1, w1 + 1024, w1 + 1024, Ff, (size_t)Dm * Ff, b1, b1 + 1024, b1 + 1024, Ff,
        hbuf16, Ff, 0, Dm, elist, Nt, ecnt, 1, 1);
    // ffn2: Y[pid] = H[pid] @ w2[e] + b2[e]  (A = bf16 H, no conversion)
    gemm_bf16_kernel<0, 1, 0><<<dim3(8, 16, 8), blk, 0, stream>>>(
        hbuf16, Ff, w2, w2, w2, Dm, (size_t)Ff * Dm, b2, b2, b2, Dm,
        ybuf, Dm, 0, Ff, elist, Nt, ecnt, 2, 0);
    moe_combine<<<(Nt * Dm) / 256, blk, 0, stream>>>(ybuf, gatep, t2);
    ln_residual_kernel<<<Nt, blk, 0, stream>>>(tb, t2, ln3_g, ln3_b, outp);
    lb_kernel<<<1, 64, 0, stream>>>(impf, cntf, outp + ND);
}

// Round 6
// 819.563 us; speedup vs baseline: 4.4254x; 1.0136x over previous
//
#include <hip/hip_runtime.h>

// Problem constants
constexpr int Dm = 1024;
constexpr int NH = 16;
constexpr int Ff = 2048;
constexpr int NE = 8;
constexpr int Bn = 4;
constexpr int Tn = 512;
constexpr int Nt = 2048;   // total tokens

typedef float  f32x4  __attribute__((ext_vector_type(4)));
typedef __bf16 bf16x8 __attribute__((ext_vector_type(8)));
typedef unsigned short u16x8 __attribute__((ext_vector_type(8)));

// fp32 -> bf16 round-to-nearest-even
__device__ inline unsigned short f2bf(float f) {
    unsigned u = __builtin_bit_cast(unsigned, f);
    u += 0x7FFFu + ((u >> 16) & 1u);
    return (unsigned short)(u >> 16);
}
__device__ inline float bf2f(unsigned short h) {
    unsigned u = (unsigned)h << 16;
    return __builtin_bit_cast(float, u);
}
__device__ inline void splitbf(float x, unsigned short& hi, unsigned short& lo) {
    hi = f2bf(x);
    lo = f2bf(x - bf2f(hi));
}
__device__ inline bf16x8 ld_frag(const unsigned short* p) {
    return __builtin_bit_cast(bf16x8, *(const u16x8*)p);
}

// ---------------------------------------------------------------------------
// Pipelined MFMA GEMM: C = act(A @ W + bias). Tile 128x128x32, 4 waves.
//  SPLIT: 3-term split-bf16 (fp32-grade) vs single bf16.
//  ABF:   A is pre-converted bf16 (pure-copy staging).
//  CBF:   C written bf16.
//  ACC:   epilogue does t2[token] += gate[pid]*val (MoE combine fused).
// Register-prefetch pipeline: next K-tile's global loads issue while MFMAs
// run on the current LDS tile (latency hiding at low occupancy).
// Optional fused second dense GEMM (blockIdx.x >= xSplit -> desc 2).
// ---------------------------------------------------------------------------
template <int SPLIT, int ABF, int CBF, int ACC>
__global__ __launch_bounds__(256) void gemm_bf16_kernel(
    const void* __restrict__ Ain, int lda,
    const float* __restrict__ W0, const float* __restrict__ W1,
    const float* __restrict__ W2, int ldw, size_t weStride,
    const float* __restrict__ B0, const float* __restrict__ B1,
    const float* __restrict__ B2, size_t beStride,
    void* __restrict__ Cout, int ldc,
    int Mparam, int K,
    const int* __restrict__ lst, int lstStride, const int* __restrict__ cnt,
    int mode, int relu,
    const void* __restrict__ Ain2, const float* __restrict__ W0b,
    const float* __restrict__ W1b, const float* __restrict__ B0b,
    const float* __restrict__ B1b, void* __restrict__ Cout2, int ldc2,
    int xSplit,
    const float* __restrict__ gatep, float* __restrict__ accOut)
{
    __shared__ __align__(16) unsigned short AsH[128 * 40];
    __shared__ __align__(16) unsigned short WsH[128 * 40];
    __shared__ __align__(16) unsigned short AsL[SPLIT ? 128 * 40 : 1];
    __shared__ __align__(16) unsigned short WsL[SPLIT ? 128 * 40 : 1];
    __shared__ int inIdx[128];
    __shared__ int outIdx[128];

    const int e = blockIdx.z;
    const int M = (mode == 0) ? Mparam : cnt[e];
    const int m0 = blockIdx.y * 128;
    if (m0 >= M) return;

    // select primary or fused-second descriptor
    int bx = blockIdx.x;
    const void* Aptr = Ain;
    void* Cptr = Cout;
    int myldc = ldc;
    const float *w0 = W0, *w1 = W1, *w2 = W2, *b0 = B0, *b1 = B1, *b2 = B2;
    if (xSplit && bx >= xSplit) {
        bx -= xSplit;
        Aptr = Ain2; Cptr = Cout2; myldc = ldc2;
        w0 = W0b; w1 = W1b; w2 = W1b; b0 = B0b; b1 = B1b; b2 = B1b;
    }
    const int n0 = bx * 128;
    const int seg = n0 >> 10;
    const float* W = ((seg == 0) ? w0 : (seg == 1) ? w1 : w2) + (size_t)e * weStride;
    const float* bias = ((seg == 0) ? b0 : (seg == 1) ? b1 : b2) + (size_t)e * beStride;
    const int nseg = n0 & 1023;
    const int tid = threadIdx.x;

    if (tid < 128) {
        int g = m0 + tid;
        bool valid = g < M;
        int gi, go;
        if (mode == 0) { gi = valid ? g : (M - 1); go = valid ? g : -1; }
        else {
            int pid = lst[(size_t)e * lstStride + (valid ? g : 0)];
            gi = (mode == 1) ? (pid >> 1) : pid;
            go = valid ? pid : -1;
        }
        inIdx[tid] = gi;
        outIdx[tid] = go;
    }
    __syncthreads();

    const int ar = tid >> 1, ahalf = tid & 1;                  // A: 2 thr/row
    const int bn = (tid & 63) * 2, bko = ((tid >> 6) & 3) * 8; // B: 2 n, 8 k
    const float* aBaseF = ABF ? nullptr
        : ((const float*)Aptr + (size_t)inIdx[ar] * lda + ahalf * 16);
    const unsigned short* aBaseB = ABF
        ? ((const unsigned short*)Aptr + (size_t)inIdx[ar] * lda + ahalf * 16)
        : nullptr;
    const float* wBase = W + (size_t)bko * ldw + nseg + bn;

    const int lane = tid & 63, wv = tid >> 6;
    const int wy = (wv >> 1) * 64, wx = (wv & 1) * 64;
    const int l15 = lane & 15, quad = lane >> 4;

    f32x4 acc[4][4];
    #pragma unroll
    for (int i = 0; i < 4; ++i)
        #pragma unroll
        for (int j = 0; j < 4; ++j) acc[i][j] = (f32x4)0.f;

    // prefetch registers
    float av[16];
    u16x8 a16[2];
    float2 wreg[8];

    auto loadA = [&](int k0) {
        if (ABF) {
            const unsigned short* ap = aBaseB + k0;
            a16[0] = *(const u16x8*)(ap);
            a16[1] = *(const u16x8*)(ap + 8);
        } else {
            const float* ap = aBaseF + k0;
            *(float4*)&av[0]  = *(const float4*)(ap);
            *(float4*)&av[4]  = *(const float4*)(ap + 4);
            *(float4*)&av[8]  = *(const float4*)(ap + 8);
            *(float4*)&av[12] = *(const float4*)(ap + 12);
        }
    };
    auto loadW = [&](int k0) {
        const float* wp = wBase + (size_t)k0 * ldw;
        #pragma unroll
        for (int j = 0; j < 8; ++j) wreg[j] = *(const float2*)(wp + (size_t)j * ldw);
    };
    auto storeA = [&]() {
        if (ABF) {
            *(u16x8*)&AsH[ar * 40 + ahalf * 16]     = a16[0];
            *(u16x8*)&AsH[ar * 40 + ahalf * 16 + 8] = a16[1];
        } else {
            u16x8 h0, h1, l0, l1;
            #pragma unroll
            for (int i = 0; i < 8; ++i) {
                if (SPLIT) {
                    unsigned short hh, ll;
                    splitbf(av[i], hh, ll); h0[i] = hh; l0[i] = ll;
                    splitbf(av[8 + i], hh, ll); h1[i] = hh; l1[i] = ll;
                } else {
                    h0[i] = f2bf(av[i]);
                    h1[i] = f2bf(av[8 + i]);
                }
            }
            *(u16x8*)&AsH[ar * 40 + ahalf * 16]     = h0;
            *(u16x8*)&AsH[ar * 40 + ahalf * 16 + 8] = h1;
            if (SPLIT) {
                *(u16x8*)&AsL[ar * 40 + ahalf * 16]     = l0;
                *(u16x8*)&AsL[ar * 40 + ahalf * 16 + 8] = l1;
            }
        }
    };
    auto storeW = [&]() {
        u16x8 h0, h1, l0, l1;
        #pragma unroll
        for (int j = 0; j < 8; ++j) {
            if (SPLIT) {
                unsigned short hh, ll;
                splitbf(wreg[j].x, hh, ll); h0[j] = hh; l0[j] = ll;
                splitbf(wreg[j].y, hh, ll); h1[j] = hh; l1[j] = ll;
            } else {
                h0[j] = f2bf(wreg[j].x);
                h1[j] = f2bf(wreg[j].y);
            }
        }
        *(u16x8*)&WsH[bn * 40 + bko]       = h0;
        *(u16x8*)&WsH[(bn + 1) * 40 + bko] = h1;
        if (SPLIT) {
            *(u16x8*)&WsL[bn * 40 + bko]       = l0;
            *(u16x8*)&WsL[(bn + 1) * 40 + bko] = l1;
        }
    };

    loadA(0);
    loadW(0);
    for (int k0 = 0; k0 < K; k0 += 32) {
        storeA();
        storeW();
        __syncthreads();
        if (k0 + 32 < K) { loadA(k0 + 32); loadW(k0 + 32); }  // prefetch next tile
        bf16x8 ah[4], bh[4], al[4], bl[4];
        #pragma unroll
        for (int mi = 0; mi < 4; ++mi)
            ah[mi] = ld_frag(&AsH[(wy + mi * 16 + l15) * 40 + quad * 8]);
        #pragma unroll
        for (int ni = 0; ni < 4; ++ni)
            bh[ni] = ld_frag(&WsH[(wx + ni * 16 + l15) * 40 + quad * 8]);
        if (SPLIT) {
            #pragma unroll
            for (int mi = 0; mi < 4; ++mi)
                al[mi] = ld_frag(&AsL[(wy + mi * 16 + l15) * 40 + quad * 8]);
            #pragma unroll
            for (int ni = 0; ni < 4; ++ni)
                bl[ni] = ld_frag(&WsL[(wx + ni * 16 + l15) * 40 + quad * 8]);
        }
        #pragma unroll
        for (int mi = 0; mi < 4; ++mi)
            #pragma unroll
            for (int ni = 0; ni < 4; ++ni) {
                acc[mi][ni] = __builtin_amdgcn_mfma_f32_16x16x32_bf16(
                    ah[mi], bh[ni], acc[mi][ni], 0, 0, 0);
                if (SPLIT) {
                    acc[mi][ni] = __builtin_amdgcn_mfma_f32_16x16x32_bf16(
                        ah[mi], bl[ni], acc[mi][ni], 0, 0, 0);
                    acc[mi][ni] = __builtin_amdgcn_mfma_f32_16x16x32_bf16(
                        al[mi], bh[ni], acc[mi][ni], 0, 0, 0);
                }
            }
        __syncthreads();
    }

    // ---- epilogue ----
    #pragma unroll
    for (int mi = 0; mi < 4; ++mi) {
        #pragma unroll
        for (int r = 0; r < 4; ++r) {
            int rl = wy + mi * 16 + quad * 4 + r;
            int orow = outIdx[rl];
            if (orow < 0) continue;
            #pragma unroll
            for (int ni = 0; ni < 4; ++ni) {
                int col = n0 + wx + ni * 16 + l15;
                float val = acc[mi][ni][r] + bias[col & 1023];
                if (relu) val = fmaxf(val, 0.f);
                if (ACC) {
                    float g = gatep[orow];
                    atomicAdd(&accOut[(size_t)(orow >> 1) * Dm + col], g * val);
                } else if (CBF) {
                    ((unsigned short*)Cptr)[(size_t)orow * myldc + col] = f2bf(val);
                } else {
                    ((float*)Cptr)[(size_t)orow * myldc + col] = val;
                }
            }
        }
    }
}

// ---------------------------------------------------------------------------
// Split-bf16 flash attention w/ register-prefetch of next K/V tile.
// Block = 64 Q rows x (b,h); 4 waves x 16 Q rows.
// ---------------------------------------------------------------------------
__global__ __launch_bounds__(256) void attn_kernel(
    const float* __restrict__ Qp, int qld,
    const float* __restrict__ Kp, int kld, int kOff,
    const float* __restrict__ Vp, int vld, int vOff,
    float* __restrict__ O)
{
    __shared__ __align__(16) unsigned short KtH[64 * 72], KtL[64 * 72];
    __shared__ __align__(16) unsigned short VtH[64 * 72], VtL[64 * 72];
    __shared__ __align__(16) unsigned short PtH[4][16 * 72], PtL[4][16 * 72];

    const int tid = threadIdx.x, lane = tid & 63, wv = tid >> 6;
    const int quad = lane >> 4, l15 = lane & 15;
    const int b = blockIdx.z, h = blockIdx.y, q0 = blockIdx.x * 64;
    const int bT = b * Tn;

    bf16x8 aqh[2], aql[2];
    {
        const float* qp = Qp + (size_t)(bT + q0 + wv * 16 + l15) * qld + h * 64;
        #pragma unroll
        for (int s = 0; s < 2; ++s) {
            float v[8];
            *(float4*)&v[0] = *(const float4*)(qp + s * 32 + quad * 8);
            *(float4*)&v[4] = *(const float4*)(qp + s * 32 + quad * 8 + 4);
            u16x8 th, tl;
            #pragma unroll
            for (int i = 0; i < 8; ++i) {
                unsigned short hh, ll;
                splitbf(v[i], hh, ll); th[i] = hh; tl[i] = ll;
            }
            aqh[s] = __builtin_bit_cast(bf16x8, th);
            aql[s] = __builtin_bit_cast(bf16x8, tl);
        }
    }

    f32x4 oacc[4];
    #pragma unroll
    for (int i = 0; i < 4; ++i) oacc[i] = (f32x4)0.f;
    float mrow[4] = {-1e30f, -1e30f, -1e30f, -1e30f};
    float lrow[4] = {0.f, 0.f, 0.f, 0.f};

    const int rr = tid >> 2, cc = tid & 3;

    float kf[16], vf[16];
    auto loadKV = [&](int kt0) {
        const float* kr = Kp + (size_t)(bT + kt0 + rr) * kld + kOff + h * 64 + cc * 16;
        *(float4*)&kf[0]  = *(const float4*)(kr);
        *(float4*)&kf[4]  = *(const float4*)(kr + 4);
        *(float4*)&kf[8]  = *(const float4*)(kr + 8);
        *(float4*)&kf[12] = *(const float4*)(kr + 12);
        const float* vr = Vp + (size_t)(bT + kt0 + rr) * vld + vOff + h * 64 + cc * 16;
        *(float4*)&vf[0]  = *(const float4*)(vr);
        *(float4*)&vf[4]  = *(const float4*)(vr + 4);
        *(float4*)&vf[8]  = *(const float4*)(vr + 8);
        *(float4*)&vf[12] = *(const float4*)(vr + 12);
    };
    auto storeKV = [&]() {
        u16x8 h0, h1, l0, l1;
        #pragma unroll
        for (int i = 0; i < 8; ++i) {
            unsigned short hh, ll;
            splitbf(kf[i], hh, ll); h0[i] = hh; l0[i] = ll;
            splitbf(kf[8 + i], hh, ll); h1[i] = hh; l1[i] = ll;
        }
        *(u16x8*)&KtH[rr * 72 + cc * 16]     = h0;
        *(u16x8*)&KtH[rr * 72 + cc * 16 + 8] = h1;
        *(u16x8*)&KtL[rr * 72 + cc * 16]     = l0;
        *(u16x8*)&KtL[rr * 72 + cc * 16 + 8] = l1;
        #pragma unroll
        for (int i = 0; i < 16; ++i) {
            unsigned short hh, ll;
            splitbf(vf[i], hh, ll);
            VtH[(cc * 16 + i) * 72 + rr] = hh;
            VtL[(cc * 16 + i) * 72 + rr] = ll;
        }
    };

    loadKV(0);
    for (int kt0 = 0; kt0 < Tn; kt0 += 64) {
        storeKV();
        __syncthreads();
        if (kt0 + 64 < Tn) loadKV(kt0 + 64);   // prefetch next K/V tile

        // ---- S = (Q K^T) * 0.125, split 3-term ----
        f32x4 sacc[4];
        #pragma unroll
        for (int nt = 0; nt < 4; ++nt) {
            sacc[nt] = (f32x4)0.f;
            #pragma unroll
            for (int s = 0; s < 2; ++s) {
                bf16x8 bkh = ld_frag(&KtH[(nt * 16 + l15) * 72 + s * 32 + quad * 8]);
                bf16x8 bkl = ld_frag(&KtL[(nt * 16 + l15) * 72 + s * 32 + quad * 8]);
                sacc[nt] = __builtin_amdgcn_mfma_f32_16x16x32_bf16(aqh[s], bkh, sacc[nt], 0, 0, 0);
                sacc[nt] = __builtin_amdgcn_mfma_f32_16x16x32_bf16(aqh[s], bkl, sacc[nt], 0, 0, 0);
                sacc[nt] = __builtin_amdgcn_mfma_f32_16x16x32_bf16(aql[s], bkh, sacc[nt], 0, 0, 0);
            }
        }
        #pragma unroll
        for (int nt = 0; nt < 4; ++nt)
            #pragma unroll
            for (int r = 0; r < 4; ++r) sacc[nt][r] *= 0.125f;

        // ---- online softmax ----
        float alpha[4], mnew[4];
        #pragma unroll
        for (int r = 0; r < 4; ++r) {
            float mx = fmaxf(fmaxf(sacc[0][r], sacc[1][r]), fmaxf(sacc[2][r], sacc[3][r]));
            #pragma unroll
            for (int msk = 1; msk < 16; msk <<= 1) mx = fmaxf(mx, __shfl_xor(mx, msk));
            mnew[r] = fmaxf(mrow[r], mx);
            alpha[r] = __expf(mrow[r] - mnew[r]);
            mrow[r] = mnew[r];
        }
        float rs[4] = {0.f, 0.f, 0.f, 0.f};
        #pragma unroll
        for (int nt = 0; nt < 4; ++nt)
            #pragma unroll
            for (int r = 0; r < 4; ++r) {
                float p = __expf(sacc[nt][r] - mnew[r]);
                sacc[nt][r] = p;
                rs[r] += p;
            }
        #pragma unroll
        for (int r = 0; r < 4; ++r) {
            #pragma unroll
            for (int msk = 1; msk < 16; msk <<= 1) rs[r] += __shfl_xor(rs[r], msk);
            lrow[r] = lrow[r] * alpha[r] + rs[r];
        }
        #pragma unroll
        for (int ni = 0; ni < 4; ++ni)
            #pragma unroll
            for (int r = 0; r < 4; ++r) oacc[ni][r] *= alpha[r];

        // ---- P: C-layout -> A-layout via per-wave LDS (hi/lo) ----
        #pragma unroll
        for (int nt = 0; nt < 4; ++nt)
            #pragma unroll
            for (int r = 0; r < 4; ++r) {
                unsigned short hh, ll;
                splitbf(sacc[nt][r], hh, ll);
                PtH[wv][(quad * 4 + r) * 72 + nt * 16 + l15] = hh;
                PtL[wv][(quad * 4 + r) * 72 + nt * 16 + l15] = ll;
            }
        asm volatile("s_waitcnt lgkmcnt(0)" ::: "memory");

        // ---- O += P @ V, split 3-term ----
        #pragma unroll
        for (int s = 0; s < 2; ++s) {
            bf16x8 aph = ld_frag(&PtH[wv][l15 * 72 + s * 32 + quad * 8]);
            bf16x8 apl = ld_frag(&PtL[wv][l15 * 72 + s * 32 + quad * 8]);
            #pragma unroll
            for (int ni = 0; ni < 4; ++ni) {
                bf16x8 bvh = ld_frag(&VtH[(ni * 16 + l15) * 72 + s * 32 + quad * 8]);
                bf16x8 bvl = ld_frag(&VtL[(ni * 16 + l15) * 72 + s * 32 + quad * 8]);
                oacc[ni] = __builtin_amdgcn_mfma_f32_16x16x32_bf16(aph, bvh, oacc[ni], 0, 0, 0);
                oacc[ni] = __builtin_amdgcn_mfma_f32_16x16x32_bf16(aph, bvl, oacc[ni], 0, 0, 0);
                oacc[ni] = __builtin_amdgcn_mfma_f32_16x16x32_bf16(apl, bvh, oacc[ni], 0, 0, 0);
            }
        }
        __syncthreads();
    }

    #pragma unroll
    for (int r = 0; r < 4; ++r) {
        float inv = 1.f / lrow[r];
        int orow = bT + q0 + wv * 16 + quad * 4 + r;
        #pragma unroll
        for (int ni = 0; ni < 4; ++ni) {
            int col = h * 64 + ni * 16 + l15;
            O[(size_t)orow * Dm + col] = oacc[ni][r] * inv;
        }
    }
}

// ---------------------------------------------------------------------------
// Fused residual + LayerNorm
// ---------------------------------------------------------------------------
__global__ __launch_bounds__(256) void ln_residual_kernel(
    const float* __restrict__ X, const float* __restrict__ R,
    const float* __restrict__ g, const float* __restrict__ bta,
    float* __restrict__ Out)
{
    __shared__ float red[8];
    const int t = blockIdx.x, tid = threadIdx.x;
    float v[4];
    float s = 0.f;
    #pragma unroll
    for (int i = 0; i < 4; ++i) {
        int c = tid + i * 256;
        v[i] = X[(size_t)t * Dm + c] + R[(size_t)t * Dm + c];
        s += v[i];
    }
    #pragma unroll
    for (int off = 32; off; off >>= 1) s += __shfl_down(s, off);
    const int wid = tid >> 6;
    if ((tid & 63) == 0) red[wid] = s;
    __syncthreads();
    const float mean = (red[0] + red[1] + red[2] + red[3]) * (1.f / 1024.f);
    float s2 = 0.f;
    #pragma unroll
    for (int i = 0; i < 4; ++i) { float d = v[i] - mean; s2 += d * d; }
    #pragma unroll
    for (int off = 32; off; off >>= 1) s2 += __shfl_down(s2, off);
    if ((tid & 63) == 0) red[4 + wid] = s2;
    __syncthreads();
    const float var  = (red[4] + red[5] + red[6] + red[7]) * (1.f / 1024.f);
    const float rstd = rsqrtf(var + 1e-5f);
    #pragma unroll
    for (int i = 0; i < 4; ++i) {
        int c = tid + i * 256;
        Out[(size_t)t * Dm + c] = (v[i] - mean) * rstd * g[c] + bta[c];
    }
}

// ---------------------------------------------------------------------------
// MoE router — LDS-aggregated stats, block-batched atomics.
// ---------------------------------------------------------------------------
constexpr int RT_TPB = 32;   // tokens per block
__global__ __launch_bounds__(256) void router_kernel(
    const float* __restrict__ X, const float* __restrict__ rw,
    const float* __restrict__ rb, float* __restrict__ gatep,
    int* __restrict__ elist, int* __restrict__ ecnt,
    float* __restrict__ impf, float* __restrict__ cntf)
{
    __shared__ float simp[NE];
    __shared__ int   scnt[NE];
    __shared__ int   sbase[NE];
    __shared__ int   sexp[RT_TPB][2];
    __shared__ int   spos[RT_TPB][2];

    const int tid = threadIdx.x, lane = tid & 63, wv = tid >> 6;
    if (tid < NE) { simp[tid] = 0.f; scnt[tid] = 0; }
    __syncthreads();

    const int t0 = blockIdx.x * RT_TPB;

    for (int i = 0; i < 8; ++i) {
        const int slot = wv * 8 + i;
        const int t = t0 + slot;
        float l[NE];
        #pragma unroll
        for (int e = 0; e < NE; ++e) l[e] = 0.f;
        #pragma unroll
        for (int j = 0; j < Dm / 64; ++j) {
            int d = lane + j * 64;
            float x = X[(size_t)t * Dm + d];
            #pragma unroll
            for (int e = 0; e < NE; ++e) l[e] += x * rw[d * NE + e];
        }
        #pragma unroll
        for (int e = 0; e < NE; ++e) {
            float vv = l[e];
            #pragma unroll
            for (int off = 32; off; off >>= 1) vv += __shfl_down(vv, off);
            l[e] = vv;
        }
        if (lane == 0) {
            float mx = -1e30f;
            #pragma unroll
            for (int e = 0; e < NE; ++e) { l[e] += rb[e]; mx = fmaxf(mx, l[e]); }
            float p[NE];
            float sum = 0.f;
            #pragma unroll
            for (int e = 0; e < NE; ++e) { p[e] = __expf(l[e] - mx); sum += p[e]; }
            const float inv = 1.f / sum;
            int e0 = 0, e1 = 0;
            float v0 = -1.f, v1 = -1.f;
            #pragma unroll
            for (int e = 0; e < NE; ++e) {
                float pe = p[e] * inv;
                atomicAdd(&simp[e], pe);
                if (pe > v0)      { v1 = v0; e1 = e0; v0 = pe; e0 = e; }
                else if (pe > v1) { v1 = pe; e1 = e; }
            }
            const float gs = 1.f / (v0 + v1);
            sexp[slot][0] = e0;
            sexp[slot][1] = e1;
            spos[slot][0] = atomicAdd(&scnt[e0], 1);
            spos[slot][1] = atomicAdd(&scnt[e1], 1);
            gatep[2 * t]     = v0 * gs;
            gatep[2 * t + 1] = v1 * gs;
        }
    }
    __syncthreads();

    if (tid < NE) {
        sbase[tid] = atomicAdd(&ecnt[tid], scnt[tid]);
        atomicAdd(&impf[tid], simp[tid]);
        atomicAdd(&cntf[tid], (float)scnt[tid]);
    }
    __syncthreads();

    if (tid < RT_TPB * 2) {
        const int slot = tid >> 1, k = tid & 1;
        const int e = sexp[slot][k];
        elist[e * Nt + sbase[e] + spos[slot][k]] = 2 * (t0 + slot) + k;
    }
}

// zero t2 accumulator (+ MoE stats on block 0)
__global__ __launch_bounds__(256) void zero_kernel(
    float* __restrict__ t2, int* __restrict__ ecnt,
    float* __restrict__ impf, float* __restrict__ cntf)
{
    int i = blockIdx.x * 256 + threadIdx.x;
    *(float4*)&t2[(size_t)i * 4] = make_float4(0.f, 0.f, 0.f, 0.f);
    if (blockIdx.x == 0 && threadIdx.x < NE) {
        ecnt[threadIdx.x] = 0;
        impf[threadIdx.x] = 0.f;
        cntf[threadIdx.x] = 0.f;
    }
}

__global__ void lb_kernel(const float* __restrict__ impf,
                          const float* __restrict__ cntf,
                          float* __restrict__ out)
{
    if (threadIdx.x == 0) {
        float s = 0.f;
        for (int e = 0; e < NE; ++e) s += cntf[e] * impf[e];
        out[0] = (float)NE * s / ((float)Nt * 2.f * (float)Nt);
    }
}

// ---------------------------------------------------------------------------
extern "C" void kernel_launch(void* const* d_in, const int* in_sizes, int n_in,
                              void* d_out, int out_size, void* d_ws, size_t ws_size,
                              hipStream_t stream)
{
    const float* tgt   = (const float*)d_in[0];
    const float* memry = (const float*)d_in[1];
    const float* sa_wq = (const float*)d_in[2];
    const float* sa_wk = (const float*)d_in[3];
    const float* sa_wv = (const float*)d_in[4];
    const float* sa_wo = (const float*)d_in[5];
    const float* ca_wq = (const float*)d_in[6];
    const float* ca_wk = (const float*)d_in[7];
    const float* ca_wv = (const float*)d_in[8];
    const float* ca_wo = (const float*)d_in[9];
    const float* sa_bq = (const float*)d_in[10];
    const float* sa_bk = (const float*)d_in[11];
    const float* sa_bv = (const float*)d_in[12];
    const float* sa_bo = (const float*)d_in[13];
    const float* ca_bq = (const float*)d_in[14];
    const float* ca_bk = (const float*)d_in[15];
    const float* ca_bv = (const float*)d_in[16];
    const float* ca_bo = (const float*)d_in[17];
    const float* ln1_g = (const float*)d_in[18];
    const float* ln2_g = (const float*)d_in[19];
    const float* ln3_g = (const float*)d_in[20];
    const float* ln1_b = (const float*)d_in[21];
    const float* ln2_b = (const float*)d_in[22];
    const float* ln3_b = (const float*)d_in[23];
    const float* rw    = (const float*)d_in[24];
    const float* rb    = (const float*)d_in[25];
    const float* w1    = (const float*)d_in[26];
    const float* b1    = (const float*)d_in[27];
    const float* w2    = (const float*)d_in[28];
    const float* b2    = (const float*)d_in[29];

    float* ws = (float*)d_ws;
    const size_t ND = (size_t)Nt * Dm;
    float* qkv  = ws;                         // [0,3) self QKV
    float* qc   = ws;                         // [0,1) cross Q (after self phase)
    unsigned short* hbuf16 = (unsigned short*)ws;  // [0,2) as u16: 4096 x Ff bf16
    float* attnO = ws + 3 * ND;               // [3,4)
    float* t2   = ws + 4 * ND;                // [4,5)  (also MoE accumulator)
    float* tb   = ws + 5 * ND;                // [5,6)
    float* kvc  = ws + 6 * ND;                // [6,8) cross K/V
    float* gatep = ws + 8 * ND;               // 2*Nt
    int*   elist = (int*)(gatep + 2 * Nt);    // NE*Nt
    int*   ecnt  = elist + NE * Nt;           // NE
    float* impf  = (float*)(ecnt + NE);       // NE
    float* cntf  = impf + NE;                 // NE
    float* outp  = (float*)d_out;

    dim3 blk(256);
    dim3 attnGrid(Tn / 64, NH, Bn);

    // ---- fused: self QKV (x<24) + cross KV (x>=24) ----
    gemm_bf16_kernel<1, 0, 0, 0><<<dim3(40, 16, 1), blk, 0, stream>>>(
        tgt, Dm, sa_wq, sa_wk, sa_wv, Dm, 0, sa_bq, sa_bk, sa_bv, 0,
        qkv, 3 * Dm, Nt, Dm, nullptr, 0, nullptr, 0, 0,
        memry, ca_wk, ca_wv, ca_bk, ca_bv, kvc, 2 * Dm, 24,
        nullptr, nullptr);
    attn_kernel<<<attnGrid, blk, 0, stream>>>(
        qkv, 3 * Dm, qkv, 3 * Dm, 1024, qkv, 3 * Dm, 2048, attnO);
    gemm_bf16_kernel<1, 0, 0, 0><<<dim3(8, 16, 1), blk, 0, stream>>>(
        attnO, Dm, sa_wo, sa_wo, sa_wo, Dm, 0, sa_bo, sa_bo, sa_bo, 0,
        t2, Dm, Nt, Dm, nullptr, 0, nullptr, 0, 0,
        nullptr, nullptr, nullptr, nullptr, nullptr, nullptr, 0, 0,
        nullptr, nullptr);
    ln_residual_kernel<<<Nt, blk, 0, stream>>>(tgt, t2, ln1_g, ln1_b, tb);

    // ---- cross-attention ----
    gemm_bf16_kernel<1, 0, 0, 0><<<dim3(8, 16, 1), blk, 0, stream>>>(
        tb, Dm, ca_wq, ca_wq, ca_wq, Dm, 0, ca_bq, ca_bq, ca_bq, 0,
        qc, Dm, Nt, Dm, nullptr, 0, nullptr, 0, 0,
        nullptr, nullptr, nullptr, nullptr, nullptr, nullptr, 0, 0,
        nullptr, nullptr);
    attn_kernel<<<attnGrid, blk, 0, stream>>>(
        qc, Dm, kvc, 2 * Dm, 0, kvc, 2 * Dm, 1024, attnO);
    gemm_bf16_kernel<1, 0, 0, 0><<<dim3(8, 16, 1), blk, 0, stream>>>(
        attnO, Dm, ca_wo, ca_wo, ca_wo, Dm, 0, ca_bo, ca_bo, ca_bo, 0,
        t2, Dm, Nt, Dm, nullptr, 0, nullptr, 0, 0,
        nullptr, nullptr, nullptr, nullptr, nullptr, nullptr, 0, 0,
        nullptr, nullptr);
    ln_residual_kernel<<<Nt, blk, 0, stream>>>(tb, t2, ln2_g, ln2_b, tb);

    // ---- MoE ----
    zero_kernel<<<(Nt * Dm) / 1024, blk, 0, stream>>>(t2, ecnt, impf, cntf);
    router_kernel<<<Nt / RT_TPB, blk, 0, stream>>>(tb, rw, rb, gatep, elist, ecnt, impf, cntf);
    // ffn1: H[pid] = relu(tb[pid>>1] @ w1[e] + b1[e]) -> bf16
    gemm_bf16_kernel<0, 0, 1, 0><<<dim3(16, 16, 8), blk, 0, stream>>>(
        tb, Dm, w1, w1 + 1024, w1 + 1024, Ff, (size_t)Dm * Ff, b1, b1 + 1024, b1 + 1024, Ff,
        hbuf16, Ff, 0, Dm, elist, Nt, ecnt, 1, 1,
        nullptr, nullptr, nullptr, nullptr, nullptr, nullptr, 0, 0,
        nullptr, nullptr);
    // ffn2 + fused gate-combine: t2[token] += gate[pid] * (H[pid] @ w2[e] + b2[e])
    gemm_bf16_kernel<0, 1, 0, 1><<<dim3(8, 16, 8), blk, 0, stream>>>(
        hbuf16, Ff, w2, w2, w2, Dm, (size_t)Ff * Dm, b2, b2, b2, Dm,
        nullptr, Dm, 0, Ff, elist, Nt, ecnt, 2, 0,
        nullptr, nullptr, nullptr, nullptr, nullptr, nullptr, 0, 0,
        gatep, t2);
    ln_residual_kernel<<<Nt, blk, 0, stream>>>(tb, t2, ln3_g, ln3_b, outp);
    lb_kernel<<<1, 64, 0, stream>>>(impf, cntf, outp + ND);
}